// Round 7
// baseline (708.844 us; speedup 1.0000x reference)
//
#include <hip/hip_runtime.h>
#include <hip/hip_bf16.h>

typedef unsigned short ushort;
typedef short bf16x8 __attribute__((ext_vector_type(8)));
typedef float f32x4 __attribute__((ext_vector_type(4)));

#define NB 8
#define SS 2048
#define DD 768
#define DKV 214
#define DKP 224
#define WROWS 256
#define THR 10.0f

__device__ __forceinline__ float bf2f(ushort u) {
  union { unsigned int i; float f; } v; v.i = ((unsigned int)u) << 16; return v.f;
}
__device__ __forceinline__ ushort f2bf(float f) {
  union { float f; unsigned int i; } v; v.f = f;
  unsigned int x = v.i;
  return (ushort)((x + 0x7fffu + ((x >> 16) & 1u)) >> 16);
}
__device__ __forceinline__ void split8v(f32x4 a, f32x4 b, bf16x8& h, bf16x8& l) {
#pragma unroll
  for (int j = 0; j < 4; ++j) {
    ushort h0 = f2bf(a[j]); h[j]     = (short)h0; l[j]     = (short)f2bf(a[j] - bf2f(h0));
    ushort h1 = f2bf(b[j]); h[j + 4] = (short)h1; l[j + 4] = (short)f2bf(b[j] - bf2f(h1));
  }
}
__device__ __forceinline__ bf16x8 cvt8v(f32x4 a, f32x4 b) {
  bf16x8 r;
#pragma unroll
  for (int j = 0; j < 4; ++j) { r[j] = (short)f2bf(a[j]); r[j + 4] = (short)f2bf(b[j]); }
  return r;
}

// ---- weight prep: split Wq,Wk -> k-packed [24][256][32] hi/lo; cvt Wv -> [24][768][32] ----
__global__ __launch_bounds__(256)
void prep_w(const float* __restrict__ Wq, const float* __restrict__ Wk,
            const float* __restrict__ Wv,
            ushort* __restrict__ Wqh, ushort* __restrict__ Wql,
            ushort* __restrict__ Wkh, ushort* __restrict__ Wkl,
            ushort* __restrict__ Wvb)
{
  const int NW = WROWS * DD;
  const int NV = DD * DD;
  for (int i = blockIdx.x * 256 + threadIdx.x; i < 2 * NW + NV; i += gridDim.x * 256) {
    if (i < NW) {
      int r = i / DD, c = i % DD;
      float v = (r < DKV) ? Wq[i] : 0.f;
      ushort h = f2bf(v);
      int d = (c >> 5) * (WROWS * 32) + r * 32 + (c & 31);
      Wqh[d] = h; Wql[d] = f2bf(v - bf2f(h));
    } else if (i < 2 * NW) {
      int j = i - NW;
      int r = j / DD, c = j % DD;
      float v = (r < DKV) ? Wk[j] : 0.f;
      ushort h = f2bf(v);
      int d = (c >> 5) * (WROWS * 32) + r * 32 + (c & 31);
      Wkh[d] = h; Wkl[d] = f2bf(v - bf2f(h));
    } else {
      int j = i - 2 * NW;
      int r = j / DD, c = j % DD;
      Wvb[(c >> 5) * (DD * 32) + r * 32 + (c & 31)] = f2bf(Wv[j]);
    }
  }
}

// ---- fused Q+K projection, 64m x 128n tiles, 1-deep A prefetch ----
__global__ __launch_bounds__(256, 4)
void gemm_qk(const float* __restrict__ x1, const float* __restrict__ x2,
             const ushort* __restrict__ Wqh, const ushort* __restrict__ Wql,
             const ushort* __restrict__ Wkh, const ushort* __restrict__ Wkl,
             const float* __restrict__ bq, const float* __restrict__ bk,
             ushort* __restrict__ Qh, ushort* __restrict__ Ql,
             ushort* __restrict__ Kh, ushort* __restrict__ Kl)
{
  const int m0 = blockIdx.x * 64;
  const int which = blockIdx.y >> 1;
  const int n0 = (blockIdx.y & 1) * 128;
  const int tid = threadIdx.x;
  const int w  = tid >> 6;
  const int l  = tid & 63;
  const int lr = l & 15;
  const int lh = l >> 4;

  const float*  A    = which ? x2 : x1;
  const ushort* Bh   = which ? Wkh : Wqh;
  const ushort* Bl   = which ? Wkl : Wql;
  const float*  bias = which ? bk : bq;
  ushort* Ch = which ? Kh : Qh;
  ushort* Cl = which ? Kl : Ql;

  const f32x4 fzero = {0.f, 0.f, 0.f, 0.f};
  f32x4 acc[8];
#pragma unroll
  for (int nt = 0; nt < 8; ++nt) acc[nt] = fzero;

  const float* arow = A + (size_t)(m0 + w * 16 + lr) * DD + lh * 8;
  const int boff = (n0 + lr) * 32 + lh * 8;

  f32x4 pa = *(const f32x4*)(arow);
  f32x4 pb = *(const f32x4*)(arow + 4);
  for (int kk = 0; kk < 24; ++kk) {
    f32x4 na = fzero, nb = fzero;
    if (kk < 23) {
      na = *(const f32x4*)(arow + (kk + 1) * 32);
      nb = *(const f32x4*)(arow + (kk + 1) * 32 + 4);
    }
    bf16x8 ah, al; split8v(pa, pb, ah, al);
    const ushort* bhp = Bh + kk * (WROWS * 32) + boff;
    const ushort* blp = Bl + kk * (WROWS * 32) + boff;
#pragma unroll
    for (int nt = 0; nt < 8; ++nt) {
      bf16x8 wh = *(const bf16x8*)(bhp + nt * 512);
      bf16x8 wl = *(const bf16x8*)(blp + nt * 512);
      acc[nt] = __builtin_amdgcn_mfma_f32_16x16x32_bf16(ah, wh, acc[nt], 0, 0, 0);
      acc[nt] = __builtin_amdgcn_mfma_f32_16x16x32_bf16(ah, wl, acc[nt], 0, 0, 0);
      acc[nt] = __builtin_amdgcn_mfma_f32_16x16x32_bf16(al, wh, acc[nt], 0, 0, 0);
    }
    pa = na; pb = nb;
  }

#pragma unroll
  for (int nt = 0; nt < 8; ++nt) {
    int n = n0 + nt * 16 + lr;
    if (n >= DKP) continue;
    float bv = (n < DKV) ? bias[n] : 0.f;
#pragma unroll
    for (int r = 0; r < 4; ++r) {
      int m = m0 + w * 16 + lh * 4 + r;
      float val = (n < DKV) ? (acc[nt][r] + bv) : 0.f;
      ushort h = f2bf(val);
      Ch[(size_t)m * DKP + n] = h;
      Cl[(size_t)m * DKP + n] = f2bf(val - bf2f(h));
    }
  }
}

// ---- V projection: 64m x 256n, grid (256,3), 1-deep A prefetch. Out Vt[b][d][s] ----
__global__ __launch_bounds__(256, 3)
void gemm_v(const float* __restrict__ A, const ushort* __restrict__ Bw,
            const float* __restrict__ bias, ushort* __restrict__ Vt)
{
  const int m0 = blockIdx.x * 64;
  const int n0 = blockIdx.y * 256;
  const int tid = threadIdx.x;
  const int w  = tid >> 6;
  const int l  = tid & 63;
  const int lr = l & 15;
  const int lh = l >> 4;

  const f32x4 fzero = {0.f, 0.f, 0.f, 0.f};
  f32x4 acc[16];
#pragma unroll
  for (int nt = 0; nt < 16; ++nt) acc[nt] = fzero;

  const float* arow = A + (size_t)(m0 + w * 16 + lr) * DD + lh * 8;
  const int boff = (n0 + lr) * 32 + lh * 8;

  f32x4 pa = *(const f32x4*)(arow);
  f32x4 pb = *(const f32x4*)(arow + 4);
  for (int kk = 0; kk < 24; ++kk) {
    f32x4 na = fzero, nb = fzero;
    if (kk < 23) {
      na = *(const f32x4*)(arow + (kk + 1) * 32);
      nb = *(const f32x4*)(arow + (kk + 1) * 32 + 4);
    }
    bf16x8 af = cvt8v(pa, pb);
    const ushort* bp = Bw + kk * (DD * 32) + boff;
#pragma unroll
    for (int nt = 0; nt < 16; ++nt) {
      bf16x8 bfr = *(const bf16x8*)(bp + nt * 512);
      acc[nt] = __builtin_amdgcn_mfma_f32_16x16x32_bf16(af, bfr, acc[nt], 0, 0, 0);
    }
    pa = na; pb = nb;
  }

  __shared__ ushort lt[256][72];
#pragma unroll
  for (int nt = 0; nt < 16; ++nt) {
    int nl = nt * 16 + lr;
    float bv = bias[n0 + nl];
#pragma unroll
    for (int r = 0; r < 4; ++r)
      lt[nl][w * 16 + lh * 4 + r] = f2bf(acc[nt][r] + bv);
  }
  __syncthreads();
  const int bb = m0 >> 11;
  const int s0 = m0 & 2047;
  for (int i = tid; i < 256 * 64; i += 256) {
    int nn = i >> 6, mm = i & 63;
    Vt[(size_t)bb * (DD * SS) + (size_t)(n0 + nn) * SS + (s0 + mm)] = lt[nn][mm];
  }
}

// ---- fused attention: SINGLE barrier per tile via deferred-max softmax ----
// e = exp(sv - m_old) computed immediately (bounded ~e^THR); max update +
// Oacc/Z rescale deferred to after the barrier, only on violation.
// Each wave tracks m_run for BOTH row halves (from part_max LDS) so it can
// rescale its full Oacc locally (no alpha broadcast). Iter 0 peeled (2 barriers).
__global__ __launch_bounds__(512, 4)
void attn_fused(const ushort* __restrict__ Qh, const ushort* __restrict__ Ql,
                const ushort* __restrict__ Kh, const ushort* __restrict__ Kl,
                const ushort* __restrict__ Vt, const float* __restrict__ isc,
                const float* __restrict__ dmask, float* __restrict__ out)
{
  const int bb = blockIdx.x & 7;          // batch <-> XCD affinity
  const int q0 = (blockIdx.x >> 3) << 5;
  const int tid = threadIdx.x;
  const int w  = tid >> 6;
  const int l  = tid & 63;
  const int lr = l & 15;
  const int lh = l >> 4;
  const int rh = w & 1;
  const int cq = w >> 1;

  __shared__ __align__(16) ushort Qlh[32][232];
  __shared__ __align__(16) ushort Qll[32][232];
  __shared__ __align__(16) ushort Plds[2][2048];
  __shared__ float part_max[2][4][32];
  __shared__ float part_sum[2][4][32];
  __shared__ float rcpZ[32];

  {
    const size_t qoff = (size_t)(bb * SS + q0) * DKP;
    for (int i = tid; i < 32 * 28; i += 512) {
      int r = i / 28, c = i % 28;
      *(bf16x8*)(&Qlh[r][c * 8]) = *(const bf16x8*)(Qh + qoff + r * DKP + c * 8);
      *(bf16x8*)(&Qll[r][c * 8]) = *(const bf16x8*)(Ql + qoff + r * DKP + c * 8);
    }
  }
  __syncthreads();

  const f32x4 fzero = {0.f, 0.f, 0.f, 0.f};
  float m_run2[2][4];                      // [row-half mt][r]
  float Z_run[4];
#pragma unroll
  for (int r = 0; r < 4; ++r) { m_run2[0][r] = -1e30f; m_run2[1][r] = -1e30f; Z_run[r] = 0.f; }
  f32x4 Oacc[2][6];
#pragma unroll
  for (int mt = 0; mt < 2; ++mt)
#pragma unroll
    for (int dt = 0; dt < 6; ++dt) Oacc[mt][dt] = fzero;

  const int qrow_w = rh * 16 + lh * 4;

  const ushort* krh = Kh + (size_t)(bb * SS + cq * 16 + lr) * DKP + lh * 8;
  const ushort* krl = Kl + (size_t)(bb * SS + cq * 16 + lr) * DKP + lh * 8;
  const float*  dmp = dmask + (size_t)bb * SS * SS + (size_t)(q0 + qrow_w) * SS + cq * 16 + lr;
  const float*  icp = isc + (size_t)(q0 + qrow_w) * SS + cq * 16 + lr;
  const ushort* vcr = Vt + (size_t)bb * (DD * SS) + (size_t)(w * 96 + lr) * SS + lh * 8;

  float icv[4];
#pragma unroll
  for (int r = 0; r < 4; ++r) icv[r] = icp[(size_t)r * SS];
  icp += 64;

  for (int it = 0; it < SS / 64; ++it) {
    const int b = it & 1;
    const bool more = (it + 1 < SS / 64);
    float dmv[4];
#pragma unroll
    for (int r = 0; r < 4; ++r) dmv[r] = dmp[(size_t)r * SS];
    // ---- QK: inline K loads, 3 accumulator chains ----
    f32x4 a0 = fzero, a1 = fzero, a2 = fzero;
    __builtin_amdgcn_s_setprio(1);
#pragma unroll
    for (int k = 0; k < 7; ++k) {
      bf16x8 kh = *(const bf16x8*)(krh + k * 32);
      bf16x8 kl = *(const bf16x8*)(krl + k * 32);
      bf16x8 ah = *(const bf16x8*)(&Qlh[rh * 16 + lr][k * 32 + lh * 8]);
      bf16x8 al = *(const bf16x8*)(&Qll[rh * 16 + lr][k * 32 + lh * 8]);
      a0 = __builtin_amdgcn_mfma_f32_16x16x32_bf16(ah, kh, a0, 0, 0, 0);
      a1 = __builtin_amdgcn_mfma_f32_16x16x32_bf16(ah, kl, a1, 0, 0, 0);
      a2 = __builtin_amdgcn_mfma_f32_16x16x32_bf16(al, kh, a2, 0, 0, 0);
    }
    __builtin_amdgcn_s_setprio(0);
    float icn[4];
    if (more) {
#pragma unroll
      for (int r = 0; r < 4; ++r) icn[r] = icp[(size_t)r * SS];
    }
    f32x4 sacc = (a0 + a1) + a2;
    float sv[4];
#pragma unroll
    for (int r = 0; r < 4; ++r) sv[r] = sacc[r] * __builtin_amdgcn_rcpf(icv[r]);
    // per-row local max over the 16-lane group
    float mx[4];
#pragma unroll
    for (int r = 0; r < 4; ++r) mx[r] = sv[r];
#pragma unroll
    for (int off = 1; off < 16; off <<= 1) {
#pragma unroll
      for (int r = 0; r < 4; ++r) mx[r] = fmaxf(mx[r], __shfl_xor(mx[r], off));
    }
    if (lr == 0) {
#pragma unroll
      for (int r = 0; r < 4; ++r) part_max[b][cq][qrow_w + r] = mx[r];
    }
    if (it == 0) {
      // peel: establish m_run from tile-0 max (extra barrier, once)
      asm volatile("s_waitcnt lgkmcnt(0)" ::: "memory");
      __builtin_amdgcn_s_barrier();
#pragma unroll
      for (int mt = 0; mt < 2; ++mt) {
#pragma unroll
        for (int r = 0; r < 4; ++r) {
          int row = mt * 16 + lh * 4 + r;
          m_run2[mt][r] = fmaxf(fmaxf(part_max[0][0][row], part_max[0][1][row]),
                                fmaxf(part_max[0][2][row], part_max[0][3][row]));
        }
      }
    }
    // e with (possibly stale) running max — bounded by e^THR
    float e[4], zl[4];
#pragma unroll
    for (int r = 0; r < 4; ++r) {
      e[r]  = __expf(sv[r] - m_run2[rh][r]);
      zl[r] = e[r];
    }
#pragma unroll
    for (int off = 1; off < 16; off <<= 1) {
#pragma unroll
      for (int r = 0; r < 4; ++r) zl[r] += __shfl_xor(zl[r], off);
    }
    if (lr == 0) {
#pragma unroll
      for (int r = 0; r < 4; ++r) part_sum[b][cq][qrow_w + r] = zl[r];
    }
#pragma unroll
    for (int r = 0; r < 4; ++r) {
      int row = qrow_w + r;
      int col = cq * 16 + lr;
      unsigned off = (unsigned)(row * 128 + col * 2) ^ (((unsigned)row & 7u) << 4);
      *(ushort*)((char*)&Plds[b][0] + off) = f2bf(e[r] * dmv[r]);
    }
    asm volatile("s_waitcnt lgkmcnt(0)" ::: "memory");
    __builtin_amdgcn_s_barrier();                     // THE barrier
    // ---- PV ----
    bf16x8 pf[2][2];
#pragma unroll
    for (int mt = 0; mt < 2; ++mt) {
#pragma unroll
      for (int ks = 0; ks < 2; ++ks) {
        int row = mt * 16 + lr;
        unsigned off = (unsigned)(row * 128 + ks * 64 + lh * 16) ^ (((unsigned)row & 7u) << 4);
        pf[mt][ks] = *(const bf16x8*)((char*)&Plds[b][0] + off);
      }
    }
    __builtin_amdgcn_s_setprio(1);
#pragma unroll
    for (int dt = 0; dt < 6; ++dt) {
#pragma unroll
      for (int ks = 0; ks < 2; ++ks) {
        bf16x8 vf = *(const bf16x8*)(vcr + (size_t)dt * 16 * SS + ks * 32);
        Oacc[0][dt] = __builtin_amdgcn_mfma_f32_16x16x32_bf16(pf[0][ks], vf, Oacc[0][dt], 0, 0, 0);
        Oacc[1][dt] = __builtin_amdgcn_mfma_f32_16x16x32_bf16(pf[1][ks], vf, Oacc[1][dt], 0, 0, 0);
      }
    }
    __builtin_amdgcn_s_setprio(0);
    // ---- post-barrier bookkeeping: Z accumulate, deferred max update ----
#pragma unroll
    for (int r = 0; r < 4; ++r) {
      int row = qrow_w + r;
      Z_run[r] += part_sum[b][0][row] + part_sum[b][1][row] +
                  part_sum[b][2][row] + part_sum[b][3][row];
    }
    if (it > 0) {
      float oal[2][4]; int need = 0;
#pragma unroll
      for (int mt = 0; mt < 2; ++mt) {
#pragma unroll
        for (int r = 0; r < 4; ++r) {
          int row = mt * 16 + lh * 4 + r;
          float mc = fmaxf(fmaxf(part_max[b][0][row], part_max[b][1][row]),
                           fmaxf(part_max[b][2][row], part_max[b][3][row]));
          bool viol = mc > m_run2[mt][r] + THR;
          oal[mt][r] = viol ? __expf(m_run2[mt][r] - mc) : 1.f;
          if (viol) m_run2[mt][r] = mc;
          need |= viol;
        }
      }
      if (__any(need)) {
#pragma unroll
        for (int mt = 0; mt < 2; ++mt)
#pragma unroll
          for (int dt = 0; dt < 6; ++dt)
#pragma unroll
            for (int r = 0; r < 4; ++r) Oacc[mt][dt][r] *= oal[mt][r];
#pragma unroll
        for (int r = 0; r < 4; ++r) Z_run[r] *= oal[rh][r];
      }
    }
    if (more) {
#pragma unroll
      for (int r = 0; r < 4; ++r) icv[r] = icn[r];
    }
    krh += 64 * DKP; krl += 64 * DKP; dmp += 64; icp += 64; vcr += 64;
  }

  if (w < 2 && lr == 0) {
#pragma unroll
    for (int r = 0; r < 4; ++r) rcpZ[qrow_w + r] = 1.0f / Z_run[r];
  }
  __syncthreads();

  float* obase = out + (size_t)(bb * SS + q0) * DD + w * 96;
#pragma unroll
  for (int mt = 0; mt < 2; ++mt) {
#pragma unroll
    for (int dt = 0; dt < 6; ++dt) {
#pragma unroll
      for (int r = 0; r < 4; ++r) {
        int row = mt * 16 + lh * 4 + r;
        obase[(size_t)row * DD + dt * 16 + lr] = Oacc[mt][dt][r] * rcpZ[row];
      }
    }
  }
}

extern "C" void kernel_launch(void* const* d_in, const int* in_sizes, int n_in,
                              void* d_out, int out_size, void* d_ws, size_t ws_size,
                              hipStream_t stream) {
  const float* x1  = (const float*)d_in[0];
  const float* x2  = (const float*)d_in[1];
  const float* x3  = (const float*)d_in[2];
  const float* Wq  = (const float*)d_in[3];
  const float* bq  = (const float*)d_in[4];
  const float* Wk  = (const float*)d_in[5];
  const float* bk  = (const float*)d_in[6];
  const float* Wv  = (const float*)d_in[7];
  const float* bv  = (const float*)d_in[8];
  const float* isc = (const float*)d_in[9];
  const float* dmk = (const float*)d_in[10];
  float* out = (float*)d_out;

  const size_t QK = (size_t)16384 * DKP;
  const size_t WN = (size_t)WROWS * DD;
  ushort* Qh  = (ushort*)d_ws;
  ushort* Ql  = Qh + QK;
  ushort* Kh  = Ql + QK;
  ushort* Kl  = Kh + QK;
  ushort* Vt  = Kl + QK;                       // [8][768][2048]
  ushort* Wqh = Vt + (size_t)NB * DD * SS;     // k-packed [24][256][32]
  ushort* Wql = Wqh + WN;
  ushort* Wkh = Wql + WN;
  ushort* Wkl = Wkh + WN;
  ushort* Wvb = Wkl + WN;                      // k-packed [24][768][32]

  dim3 blk(256);
  prep_w<<<dim3(512), blk, 0, stream>>>(Wq, Wk, Wv, Wqh, Wql, Wkh, Wkl, Wvb);
  gemm_qk<<<dim3(256, 4), blk, 0, stream>>>(x1, x2, Wqh, Wql, Wkh, Wkl, bq, bk,
                                            Qh, Ql, Kh, Kl);
  gemm_v <<<dim3(256, 3), blk, 0, stream>>>(x3, Wvb, bv, Vt);
  attn_fused<<<dim3(512), dim3(512), 0, stream>>>(Qh, Ql, Kh, Kl, Vt, isc, dmk, out);
}

// Round 8
// 573.442 us; speedup vs baseline: 1.2361x; 1.2361x over previous
//
#include <hip/hip_runtime.h>
#include <hip/hip_bf16.h>

typedef unsigned short ushort;
typedef short bf16x8 __attribute__((ext_vector_type(8)));
typedef float f32x4 __attribute__((ext_vector_type(4)));

#define NB 8
#define SS 2048
#define DD 768
#define DKV 214
#define DKP 224
#define WROWS 256

__device__ __forceinline__ float bf2f(ushort u) {
  union { unsigned int i; float f; } v; v.i = ((unsigned int)u) << 16; return v.f;
}
__device__ __forceinline__ ushort f2bf(float f) {
  union { float f; unsigned int i; } v; v.f = f;
  unsigned int x = v.i;
  return (ushort)((x + 0x7fffu + ((x >> 16) & 1u)) >> 16);
}
__device__ __forceinline__ void split8v(f32x4 a, f32x4 b, bf16x8& h, bf16x8& l) {
#pragma unroll
  for (int j = 0; j < 4; ++j) {
    ushort h0 = f2bf(a[j]); h[j]     = (short)h0; l[j]     = (short)f2bf(a[j] - bf2f(h0));
    ushort h1 = f2bf(b[j]); h[j + 4] = (short)h1; l[j + 4] = (short)f2bf(b[j] - bf2f(h1));
  }
}
__device__ __forceinline__ bf16x8 cvt8v(f32x4 a, f32x4 b) {
  bf16x8 r;
#pragma unroll
  for (int j = 0; j < 4; ++j) { r[j] = (short)f2bf(a[j]); r[j + 4] = (short)f2bf(b[j]); }
  return r;
}

// ---- weight prep: split Wq,Wk -> k-packed [24][256][32] hi/lo; cvt Wv -> [24][768][32] ----
__global__ __launch_bounds__(256)
void prep_w(const float* __restrict__ Wq, const float* __restrict__ Wk,
            const float* __restrict__ Wv,
            ushort* __restrict__ Wqh, ushort* __restrict__ Wql,
            ushort* __restrict__ Wkh, ushort* __restrict__ Wkl,
            ushort* __restrict__ Wvb)
{
  const int NW = WROWS * DD;
  const int NV = DD * DD;
  for (int i = blockIdx.x * 256 + threadIdx.x; i < 2 * NW + NV; i += gridDim.x * 256) {
    if (i < NW) {
      int r = i / DD, c = i % DD;
      float v = (r < DKV) ? Wq[i] : 0.f;
      ushort h = f2bf(v);
      int d = (c >> 5) * (WROWS * 32) + r * 32 + (c & 31);
      Wqh[d] = h; Wql[d] = f2bf(v - bf2f(h));
    } else if (i < 2 * NW) {
      int j = i - NW;
      int r = j / DD, c = j % DD;
      float v = (r < DKV) ? Wk[j] : 0.f;
      ushort h = f2bf(v);
      int d = (c >> 5) * (WROWS * 32) + r * 32 + (c & 31);
      Wkh[d] = h; Wkl[d] = f2bf(v - bf2f(h));
    } else {
      int j = i - 2 * NW;
      int r = j / DD, c = j % DD;
      Wvb[(c >> 5) * (DD * 32) + r * 32 + (c & 31)] = f2bf(Wv[j]);
    }
  }
}

// ---- fused Q+K projection, 64m x 128n tiles, 1-deep A prefetch ----
__global__ __launch_bounds__(256, 4)
void gemm_qk(const float* __restrict__ x1, const float* __restrict__ x2,
             const ushort* __restrict__ Wqh, const ushort* __restrict__ Wql,
             const ushort* __restrict__ Wkh, const ushort* __restrict__ Wkl,
             const float* __restrict__ bq, const float* __restrict__ bk,
             ushort* __restrict__ Qh, ushort* __restrict__ Ql,
             ushort* __restrict__ Kh, ushort* __restrict__ Kl)
{
  const int m0 = blockIdx.x * 64;
  const int which = blockIdx.y >> 1;
  const int n0 = (blockIdx.y & 1) * 128;
  const int tid = threadIdx.x;
  const int w  = tid >> 6;
  const int l  = tid & 63;
  const int lr = l & 15;
  const int lh = l >> 4;

  const float*  A    = which ? x2 : x1;
  const ushort* Bh   = which ? Wkh : Wqh;
  const ushort* Bl   = which ? Wkl : Wql;
  const float*  bias = which ? bk : bq;
  ushort* Ch = which ? Kh : Qh;
  ushort* Cl = which ? Kl : Ql;

  const f32x4 fzero = {0.f, 0.f, 0.f, 0.f};
  f32x4 acc[8];
#pragma unroll
  for (int nt = 0; nt < 8; ++nt) acc[nt] = fzero;

  const float* arow = A + (size_t)(m0 + w * 16 + lr) * DD + lh * 8;
  const int boff = (n0 + lr) * 32 + lh * 8;

  f32x4 pa = *(const f32x4*)(arow);
  f32x4 pb = *(const f32x4*)(arow + 4);
  for (int kk = 0; kk < 24; ++kk) {
    f32x4 na = fzero, nb = fzero;
    if (kk < 23) {
      na = *(const f32x4*)(arow + (kk + 1) * 32);
      nb = *(const f32x4*)(arow + (kk + 1) * 32 + 4);
    }
    bf16x8 ah, al; split8v(pa, pb, ah, al);
    const ushort* bhp = Bh + kk * (WROWS * 32) + boff;
    const ushort* blp = Bl + kk * (WROWS * 32) + boff;
#pragma unroll
    for (int nt = 0; nt < 8; ++nt) {
      bf16x8 wh = *(const bf16x8*)(bhp + nt * 512);
      bf16x8 wl = *(const bf16x8*)(blp + nt * 512);
      acc[nt] = __builtin_amdgcn_mfma_f32_16x16x32_bf16(ah, wh, acc[nt], 0, 0, 0);
      acc[nt] = __builtin_amdgcn_mfma_f32_16x16x32_bf16(ah, wl, acc[nt], 0, 0, 0);
      acc[nt] = __builtin_amdgcn_mfma_f32_16x16x32_bf16(al, wh, acc[nt], 0, 0, 0);
    }
    pa = na; pb = nb;
  }

#pragma unroll
  for (int nt = 0; nt < 8; ++nt) {
    int n = n0 + nt * 16 + lr;
    if (n >= DKP) continue;
    float bv = (n < DKV) ? bias[n] : 0.f;
#pragma unroll
    for (int r = 0; r < 4; ++r) {
      int m = m0 + w * 16 + lh * 4 + r;
      float val = (n < DKV) ? (acc[nt][r] + bv) : 0.f;
      ushort h = f2bf(val);
      Ch[(size_t)m * DKP + n] = h;
      Cl[(size_t)m * DKP + n] = f2bf(val - bf2f(h));
    }
  }
}

// ---- V projection: 64m x 256n, grid (256,3), 1-deep A prefetch. Out Vt[b][d][s] ----
__global__ __launch_bounds__(256, 3)
void gemm_v(const float* __restrict__ A, const ushort* __restrict__ Bw,
            const float* __restrict__ bias, ushort* __restrict__ Vt)
{
  const int m0 = blockIdx.x * 64;
  const int n0 = blockIdx.y * 256;
  const int tid = threadIdx.x;
  const int w  = tid >> 6;
  const int l  = tid & 63;
  const int lr = l & 15;
  const int lh = l >> 4;

  const f32x4 fzero = {0.f, 0.f, 0.f, 0.f};
  f32x4 acc[16];
#pragma unroll
  for (int nt = 0; nt < 16; ++nt) acc[nt] = fzero;

  const float* arow = A + (size_t)(m0 + w * 16 + lr) * DD + lh * 8;
  const int boff = (n0 + lr) * 32 + lh * 8;

  f32x4 pa = *(const f32x4*)(arow);
  f32x4 pb = *(const f32x4*)(arow + 4);
  for (int kk = 0; kk < 24; ++kk) {
    f32x4 na = fzero, nb = fzero;
    if (kk < 23) {
      na = *(const f32x4*)(arow + (kk + 1) * 32);
      nb = *(const f32x4*)(arow + (kk + 1) * 32 + 4);
    }
    bf16x8 af = cvt8v(pa, pb);
    const ushort* bp = Bw + kk * (DD * 32) + boff;
#pragma unroll
    for (int nt = 0; nt < 16; ++nt) {
      bf16x8 bfr = *(const bf16x8*)(bp + nt * 512);
      acc[nt] = __builtin_amdgcn_mfma_f32_16x16x32_bf16(af, bfr, acc[nt], 0, 0, 0);
    }
    pa = na; pb = nb;
  }

  __shared__ ushort lt[256][72];
#pragma unroll
  for (int nt = 0; nt < 16; ++nt) {
    int nl = nt * 16 + lr;
    float bv = bias[n0 + nl];
#pragma unroll
    for (int r = 0; r < 4; ++r)
      lt[nl][w * 16 + lh * 4 + r] = f2bf(acc[nt][r] + bv);
  }
  __syncthreads();
  const int bb = m0 >> 11;
  const int s0 = m0 & 2047;
  for (int i = tid; i < 256 * 64; i += 256) {
    int nn = i >> 6, mm = i & 63;
    Vt[(size_t)bb * (DD * SS) + (size_t)(n0 + nn) * SS + (s0 + mm)] = lt[nn][mm];
  }
}

// ---- fused attention: 64 q-rows, 16 waves, LDS-staged K ----
// Grid 256 = 1 block/CU (LDS-bound, 140 KB). bb = bid&7 (XCD affinity): all 32
// blocks of an XCD scan the SAME K/V tiles in lockstep -> L2-resident.
// Wave w: S-tile rows rg=w&3 (*16), cols cg=w>>2 (*16); PV d-slice w*48.
// R6's 2-barrier alpha-broadcast softmax (register-lean; no deferred max).
// K single-buffered in LDS: QK reads pre-A; stage loads post-A, ds_writes
// pre-B (lgkm drained at B) -> ready for next iter's QK. P/part arrays dbuf.
__global__ __launch_bounds__(1024, 4)
void attn_fused(const ushort* __restrict__ Qh, const ushort* __restrict__ Ql,
                const ushort* __restrict__ Kh, const ushort* __restrict__ Kl,
                const ushort* __restrict__ Vt, const float* __restrict__ isc,
                const float* __restrict__ dmask, float* __restrict__ out)
{
  const int bb = blockIdx.x & 7;
  const int q0 = (blockIdx.x >> 3) << 6;
  const int tid = threadIdx.x;
  const int w  = tid >> 6;
  const int l  = tid & 63;
  const int lr = l & 15;
  const int lh = l >> 4;
  const int rg = w & 3;
  const int cg = w >> 2;

  __shared__ __align__(16) ushort Qlh[64][232];
  __shared__ __align__(16) ushort Qll[64][232];
  __shared__ __align__(16) ushort Klh[64][232];
  __shared__ __align__(16) ushort Kll[64][232];
  __shared__ __align__(16) ushort Plds[2][4096];   // [64][64] bf16, XOR-swizzled
  __shared__ float part_max[2][4][64];
  __shared__ float part_sum[2][4][64];
  __shared__ float alpha_l[2][64];
  __shared__ float rcpZ[64];

  // ---- prologue: stage Q tile and K tile 0 ----
  {
    const size_t qoff = (size_t)(bb * SS + q0) * DKP;
    const size_t koff = (size_t)(bb * SS) * DKP;
    for (int c = tid; c < 64 * 28; c += 1024) {
      int r = c / 28, c8 = (c % 28) * 8;
      *(bf16x8*)(&Qlh[r][c8]) = *(const bf16x8*)(Qh + qoff + r * DKP + c8);
      *(bf16x8*)(&Qll[r][c8]) = *(const bf16x8*)(Ql + qoff + r * DKP + c8);
      *(bf16x8*)(&Klh[r][c8]) = *(const bf16x8*)(Kh + koff + r * DKP + c8);
      *(bf16x8*)(&Kll[r][c8]) = *(const bf16x8*)(Kl + koff + r * DKP + c8);
    }
  }
  __syncthreads();

  const f32x4 fzero = {0.f, 0.f, 0.f, 0.f};
  float m_run[4], Z_run[4];
#pragma unroll
  for (int r = 0; r < 4; ++r) { m_run[r] = -1e30f; Z_run[r] = 0.f; }
  f32x4 Oacc[4][3];
#pragma unroll
  for (int rt = 0; rt < 4; ++rt)
#pragma unroll
    for (int dt = 0; dt < 3; ++dt) Oacc[rt][dt] = fzero;

  const int qrow_w = rg * 16 + lh * 4;   // wave's S-tile rows (block-local)

  // staging assignment (constant per thread): chunks c0=tid, c1=tid+1024
  const int r0 = tid / 28,          o0 = (tid % 28) * 8;
  const int c1 = tid + 1024;
  const int r1 = c1 / 28,           o1 = (c1 % 28) * 8;
  const bool has1 = (c1 < 64 * 28);

  const float*  dmp = dmask + (size_t)bb * SS * SS + (size_t)(q0 + qrow_w) * SS + cg * 16 + lr;
  const float*  icp = isc + (size_t)(q0 + qrow_w) * SS + cg * 16 + lr;
  const ushort* vcr = Vt + (size_t)bb * (DD * SS) + (size_t)(w * 48 + lr) * SS + lh * 8;
  const ushort* knh = Kh + (size_t)(bb * SS + 64) * DKP;   // next K tile base
  const ushort* knl = Kl + (size_t)(bb * SS + 64) * DKP;

  float icv[4];
#pragma unroll
  for (int r = 0; r < 4; ++r) icv[r] = icp[(size_t)r * SS];
  icp += 64;

  for (int it = 0; it < SS / 64; ++it) {
    const int b = it & 1;
    const bool more = (it + 1 < SS / 64);
    // dropout mask for this tile (cold HBM stream; consumed at P write)
    float dmv[4];
#pragma unroll
    for (int r = 0; r < 4; ++r) dmv[r] = dmp[(size_t)r * SS];
    // ---- QK from LDS (Q and K both staged), 2 accumulator chains ----
    f32x4 a0 = fzero, a1 = fzero;
    __builtin_amdgcn_s_setprio(1);
#pragma unroll
    for (int k = 0; k < 7; ++k) {
      bf16x8 bh = *(const bf16x8*)(&Klh[cg * 16 + lr][k * 32 + lh * 8]);
      bf16x8 bl = *(const bf16x8*)(&Kll[cg * 16 + lr][k * 32 + lh * 8]);
      bf16x8 ah = *(const bf16x8*)(&Qlh[rg * 16 + lr][k * 32 + lh * 8]);
      bf16x8 al = *(const bf16x8*)(&Qll[rg * 16 + lr][k * 32 + lh * 8]);
      a0 = __builtin_amdgcn_mfma_f32_16x16x32_bf16(ah, bh, a0, 0, 0, 0);
      a1 = __builtin_amdgcn_mfma_f32_16x16x32_bf16(ah, bl, a1, 0, 0, 0);
      a1 = __builtin_amdgcn_mfma_f32_16x16x32_bf16(al, bh, a1, 0, 0, 0);
    }
    __builtin_amdgcn_s_setprio(0);
    // next-tile inv_scale prefetch
    float icn[4];
    if (more) {
#pragma unroll
      for (int r = 0; r < 4; ++r) icn[r] = icp[(size_t)r * SS];
    }
    f32x4 sacc = a0 + a1;
    float sv[4];
#pragma unroll
    for (int r = 0; r < 4; ++r) sv[r] = sacc[r] * __builtin_amdgcn_rcpf(icv[r]);
    // row max over the 16-lane group
    float mx[4];
#pragma unroll
    for (int r = 0; r < 4; ++r) mx[r] = sv[r];
#pragma unroll
    for (int off = 1; off < 16; off <<= 1) {
#pragma unroll
      for (int r = 0; r < 4; ++r) mx[r] = fmaxf(mx[r], __shfl_xor(mx[r], off));
    }
    if (lr == 0) {
#pragma unroll
      for (int r = 0; r < 4; ++r) part_max[b][cg][qrow_w + r] = mx[r];
    }
    asm volatile("s_waitcnt lgkmcnt(0)" ::: "memory");
    __builtin_amdgcn_s_barrier();                     // barrier A
    // ---- issue next K tile global loads (K LDS free to overwrite now) ----
    bf16x8 k0h, k0l, k1h, k1l;
    if (more) {
      k0h = *(const bf16x8*)(knh + r0 * DKP + o0);
      k0l = *(const bf16x8*)(knl + r0 * DKP + o0);
      if (has1) {
        k1h = *(const bf16x8*)(knh + r1 * DKP + o1);
        k1l = *(const bf16x8*)(knl + r1 * DKP + o1);
      }
    }
    // ---- combine col-groups, online update ----
    float alpha[4], e[4], zl[4];
#pragma unroll
    for (int r = 0; r < 4; ++r) {
      int row = qrow_w + r;
      float mt4 = fmaxf(fmaxf(part_max[b][0][row], part_max[b][1][row]),
                        fmaxf(part_max[b][2][row], part_max[b][3][row]));
      float mnew = fmaxf(m_run[r], mt4);
      alpha[r] = __expf(m_run[r] - mnew);
      m_run[r] = mnew;
      e[r]  = __expf(sv[r] - mnew);
      zl[r] = e[r];
    }
#pragma unroll
    for (int off = 1; off < 16; off <<= 1) {
#pragma unroll
      for (int r = 0; r < 4; ++r) zl[r] += __shfl_xor(zl[r], off);
    }
    if (lr == 0) {
#pragma unroll
      for (int r = 0; r < 4; ++r) part_sum[b][cg][qrow_w + r] = zl[r];
      if (cg == 0) {
#pragma unroll
        for (int r = 0; r < 4; ++r) alpha_l[b][qrow_w + r] = alpha[r];
      }
    }
    // ---- P = e * dropout (post-normalization mask; Z unmasked) ----
#pragma unroll
    for (int r = 0; r < 4; ++r) {
      int row = qrow_w + r;
      int col = cg * 16 + lr;
      unsigned off = (unsigned)(row * 128 + col * 2) ^ (((unsigned)row & 7u) << 4);
      *(ushort*)((char*)&Plds[b][0] + off) = f2bf(e[r] * dmv[r]);
    }
    // ---- write next K tile into LDS (compiler waits vmcnt on the regs) ----
    if (more) {
      *(bf16x8*)(&Klh[r0][o0]) = k0h;
      *(bf16x8*)(&Kll[r0][o0]) = k0l;
      if (has1) {
        *(bf16x8*)(&Klh[r1][o1]) = k1h;
        *(bf16x8*)(&Kll[r1][o1]) = k1l;
      }
    }
    asm volatile("s_waitcnt lgkmcnt(0)" ::: "memory");
    __builtin_amdgcn_s_barrier();                     // barrier B
    // ---- Z update + O rescale (alpha via LDS broadcast) ----
#pragma unroll
    for (int r = 0; r < 4; ++r) {
      int row = qrow_w + r;
      Z_run[r] = Z_run[r] * alpha[r] +
                 part_sum[b][0][row] + part_sum[b][1][row] +
                 part_sum[b][2][row] + part_sum[b][3][row];
    }
    {
      f32x4 av[4]; int need = 0;
#pragma unroll
      for (int rt = 0; rt < 4; ++rt) {
        av[rt] = *(const f32x4*)(&alpha_l[b][rt * 16 + lh * 4]);
#pragma unroll
        for (int r = 0; r < 4; ++r) need |= (av[rt][r] != 1.f);
      }
      if (__any(need)) {
#pragma unroll
        for (int rt = 0; rt < 4; ++rt)
#pragma unroll
          for (int dt = 0; dt < 3; ++dt)
#pragma unroll
            for (int r = 0; r < 4; ++r) Oacc[rt][dt][r] *= av[rt][r];
      }
    }
    // ---- PV: P frags from swizzled LDS (re-read per dt; 2 live), V global ----
    __builtin_amdgcn_s_setprio(1);
#pragma unroll
    for (int dt = 0; dt < 3; ++dt) {
#pragma unroll
      for (int ks = 0; ks < 2; ++ks) {
        bf16x8 vf = *(const bf16x8*)(vcr + (size_t)dt * 16 * SS + ks * 32);
#pragma unroll
        for (int rt = 0; rt < 4; ++rt) {
          int row = rt * 16 + lr;
          unsigned off = (unsigned)(row * 128 + ks * 64 + lh * 16) ^ (((unsigned)row & 7u) << 4);
          bf16x8 pf = *(const bf16x8*)((char*)&Plds[b][0] + off);
          Oacc[rt][dt] = __builtin_amdgcn_mfma_f32_16x16x32_bf16(pf, vf, Oacc[rt][dt], 0, 0, 0);
        }
      }
    }
    __builtin_amdgcn_s_setprio(0);
    if (more) {
#pragma unroll
      for (int r = 0; r < 4; ++r) icv[r] = icn[r];
    }
    dmp += 64; icp += 64; vcr += 64;
    knh += 64 * DKP; knl += 64 * DKP;
  }

  if (cg == 0 && lr == 0) {
#pragma unroll
    for (int r = 0; r < 4; ++r) rcpZ[qrow_w + r] = 1.0f / Z_run[r];
  }
  __syncthreads();

  float* obase = out + (size_t)(bb * SS + q0) * DD + w * 48;
#pragma unroll
  for (int rt = 0; rt < 4; ++rt) {
#pragma unroll
    for (int dt = 0; dt < 3; ++dt) {
#pragma unroll
      for (int r = 0; r < 4; ++r) {
        int row = rt * 16 + lh * 4 + r;
        obase[(size_t)row * DD + dt * 16 + lr] = Oacc[rt][dt][r] * rcpZ[row];
      }
    }
  }
}

extern "C" void kernel_launch(void* const* d_in, const int* in_sizes, int n_in,
                              void* d_out, int out_size, void* d_ws, size_t ws_size,
                              hipStream_t stream) {
  const float* x1  = (const float*)d_in[0];
  const float* x2  = (const float*)d_in[1];
  const float* x3  = (const float*)d_in[2];
  const float* Wq  = (const float*)d_in[3];
  const float* bq  = (const float*)d_in[4];
  const float* Wk  = (const float*)d_in[5];
  const float* bk  = (const float*)d_in[6];
  const float* Wv  = (const float*)d_in[7];
  const float* bv  = (const float*)d_in[8];
  const float* isc = (const float*)d_in[9];
  const float* dmk = (const float*)d_in[10];
  float* out = (float*)d_out;

  const size_t QK = (size_t)16384 * DKP;
  const size_t WN = (size_t)WROWS * DD;
  ushort* Qh  = (ushort*)d_ws;
  ushort* Ql  = Qh + QK;
  ushort* Kh  = Ql + QK;
  ushort* Kl  = Kh + QK;
  ushort* Vt  = Kl + QK;                       // [8][768][2048]
  ushort* Wqh = Vt + (size_t)NB * DD * SS;     // k-packed [24][256][32]
  ushort* Wql = Wqh + WN;
  ushort* Wkh = Wql + WN;
  ushort* Wkl = Wkh + WN;
  ushort* Wvb = Wkl + WN;                      // k-packed [24][768][32]

  dim3 blk(256);
  prep_w<<<dim3(512), blk, 0, stream>>>(Wq, Wk, Wv, Wqh, Wql, Wkh, Wkl, Wvb);
  gemm_qk<<<dim3(256, 4), blk, 0, stream>>>(x1, x2, Wqh, Wql, Wkh, Wkl, bq, bk,
                                            Qh, Ql, Kh, Kl);
  gemm_v <<<dim3(256, 3), blk, 0, stream>>>(x3, Wvb, bv, Vt);
  attn_fused<<<dim3(256), dim3(1024), 0, stream>>>(Qh, Ql, Kh, Kl, Vt, isc, dmk, out);
}

// Round 9
// 512.188 us; speedup vs baseline: 1.3840x; 1.1196x over previous
//
#include <hip/hip_runtime.h>
#include <hip/hip_bf16.h>

typedef unsigned short ushort;
typedef short bf16x8 __attribute__((ext_vector_type(8)));
typedef float f32x4 __attribute__((ext_vector_type(4)));

#define NB 8
#define SS 2048
#define DD 768
#define DKV 214
#define DKP 224
#define WROWS 256
#define MSHIFT 40.0f

__device__ __forceinline__ float bf2f(ushort u) {
  union { unsigned int i; float f; } v; v.i = ((unsigned int)u) << 16; return v.f;
}
__device__ __forceinline__ ushort f2bf(float f) {
  union { float f; unsigned int i; } v; v.f = f;
  unsigned int x = v.i;
  return (ushort)((x + 0x7fffu + ((x >> 16) & 1u)) >> 16);
}
__device__ __forceinline__ void split8v(f32x4 a, f32x4 b, bf16x8& h, bf16x8& l) {
#pragma unroll
  for (int j = 0; j < 4; ++j) {
    ushort h0 = f2bf(a[j]); h[j]     = (short)h0; l[j]     = (short)f2bf(a[j] - bf2f(h0));
    ushort h1 = f2bf(b[j]); h[j + 4] = (short)h1; l[j + 4] = (short)f2bf(b[j] - bf2f(h1));
  }
}
__device__ __forceinline__ bf16x8 cvt8v(f32x4 a, f32x4 b) {
  bf16x8 r;
#pragma unroll
  for (int j = 0; j < 4; ++j) { r[j] = (short)f2bf(a[j]); r[j + 4] = (short)f2bf(b[j]); }
  return r;
}

// ---- weight prep + Z zero. Wq,Wk -> k-packed [24][256][32] hi/lo; Wv -> [24][768][32] ----
__global__ __launch_bounds__(256)
void prep_w(const float* __restrict__ Wq, const float* __restrict__ Wk,
            const float* __restrict__ Wv,
            ushort* __restrict__ Wqh, ushort* __restrict__ Wql,
            ushort* __restrict__ Wkh, ushort* __restrict__ Wkl,
            ushort* __restrict__ Wvb, float* __restrict__ Z)
{
  const int NW = WROWS * DD;
  const int NV = DD * DD;
  for (int i = blockIdx.x * 256 + threadIdx.x; i < NB * SS; i += gridDim.x * 256)
    Z[i] = 0.f;
  for (int i = blockIdx.x * 256 + threadIdx.x; i < 2 * NW + NV; i += gridDim.x * 256) {
    if (i < NW) {
      int r = i / DD, c = i % DD;
      float v = (r < DKV) ? Wq[i] : 0.f;
      ushort h = f2bf(v);
      int d = (c >> 5) * (WROWS * 32) + r * 32 + (c & 31);
      Wqh[d] = h; Wql[d] = f2bf(v - bf2f(h));
    } else if (i < 2 * NW) {
      int j = i - NW;
      int r = j / DD, c = j % DD;
      float v = (r < DKV) ? Wk[j] : 0.f;
      ushort h = f2bf(v);
      int d = (c >> 5) * (WROWS * 32) + r * 32 + (c & 31);
      Wkh[d] = h; Wkl[d] = f2bf(v - bf2f(h));
    } else {
      int j = i - 2 * NW;
      int r = j / DD, c = j % DD;
      Wvb[(c >> 5) * (DD * 32) + r * 32 + (c & 31)] = f2bf(Wv[j]);
    }
  }
}

// ---- fused Q+K projection -> k-packed hi/lo [b][7][2048][32] ----
__global__ __launch_bounds__(256, 4)
void gemm_qk(const float* __restrict__ x1, const float* __restrict__ x2,
             const ushort* __restrict__ Wqh, const ushort* __restrict__ Wql,
             const ushort* __restrict__ Wkh, const ushort* __restrict__ Wkl,
             const float* __restrict__ bq, const float* __restrict__ bk,
             ushort* __restrict__ Qph, ushort* __restrict__ Qpl,
             ushort* __restrict__ Kph, ushort* __restrict__ Kpl)
{
  const int m0 = blockIdx.x * 64;
  const int which = blockIdx.y >> 1;
  const int n0 = (blockIdx.y & 1) * 128;
  const int tid = threadIdx.x;
  const int w  = tid >> 6;
  const int l  = tid & 63;
  const int lr = l & 15;
  const int lh = l >> 4;

  const float*  A    = which ? x2 : x1;
  const ushort* Bh   = which ? Wkh : Wqh;
  const ushort* Bl   = which ? Wkl : Wql;
  const float*  bias = which ? bk : bq;
  ushort* Ch = which ? Kph : Qph;
  ushort* Cl = which ? Kpl : Qpl;

  const f32x4 fzero = {0.f, 0.f, 0.f, 0.f};
  f32x4 acc[8];
#pragma unroll
  for (int nt = 0; nt < 8; ++nt) acc[nt] = fzero;

  const float* arow = A + (size_t)(m0 + w * 16 + lr) * DD + lh * 8;
  const int boff = (n0 + lr) * 32 + lh * 8;

  f32x4 pa = *(const f32x4*)(arow);
  f32x4 pb = *(const f32x4*)(arow + 4);
  for (int kk = 0; kk < 24; ++kk) {
    f32x4 na = fzero, nb = fzero;
    if (kk < 23) {
      na = *(const f32x4*)(arow + (kk + 1) * 32);
      nb = *(const f32x4*)(arow + (kk + 1) * 32 + 4);
    }
    bf16x8 ah, al; split8v(pa, pb, ah, al);
    const ushort* bhp = Bh + kk * (WROWS * 32) + boff;
    const ushort* blp = Bl + kk * (WROWS * 32) + boff;
#pragma unroll
    for (int nt = 0; nt < 8; ++nt) {
      bf16x8 wh = *(const bf16x8*)(bhp + nt * 512);
      bf16x8 wl = *(const bf16x8*)(blp + nt * 512);
      acc[nt] = __builtin_amdgcn_mfma_f32_16x16x32_bf16(ah, wh, acc[nt], 0, 0, 0);
      acc[nt] = __builtin_amdgcn_mfma_f32_16x16x32_bf16(ah, wl, acc[nt], 0, 0, 0);
      acc[nt] = __builtin_amdgcn_mfma_f32_16x16x32_bf16(al, wh, acc[nt], 0, 0, 0);
    }
    pa = na; pb = nb;
  }

#pragma unroll
  for (int nt = 0; nt < 8; ++nt) {
    int n = n0 + nt * 16 + lr;
    if (n >= DKP) continue;
    float bv = (n < DKV) ? bias[n] : 0.f;
#pragma unroll
    for (int r = 0; r < 4; ++r) {
      int m = m0 + w * 16 + lh * 4 + r;
      int bb = m >> 11, s = m & 2047;
      float val = (n < DKV) ? (acc[nt][r] + bv) : 0.f;
      ushort h = f2bf(val);
      size_t idx = ((size_t)(bb * 7 + (n >> 5)) * SS + s) * 32 + (n & 31);
      Ch[idx] = h;
      Cl[idx] = f2bf(val - bf2f(h));
    }
  }
}

// ---- V projection -> k-packed Vp[b][64][768][32] ----
__global__ __launch_bounds__(256, 3)
void gemm_v(const float* __restrict__ A, const ushort* __restrict__ Bw,
            const float* __restrict__ bias, ushort* __restrict__ Vp)
{
  const int m0 = blockIdx.x * 64;
  const int n0 = blockIdx.y * 256;
  const int tid = threadIdx.x;
  const int w  = tid >> 6;
  const int l  = tid & 63;
  const int lr = l & 15;
  const int lh = l >> 4;

  const f32x4 fzero = {0.f, 0.f, 0.f, 0.f};
  f32x4 acc[16];
#pragma unroll
  for (int nt = 0; nt < 16; ++nt) acc[nt] = fzero;

  const float* arow = A + (size_t)(m0 + w * 16 + lr) * DD + lh * 8;
  const int boff = (n0 + lr) * 32 + lh * 8;

  f32x4 pa = *(const f32x4*)(arow);
  f32x4 pb = *(const f32x4*)(arow + 4);
  for (int kk = 0; kk < 24; ++kk) {
    f32x4 na = fzero, nb = fzero;
    if (kk < 23) {
      na = *(const f32x4*)(arow + (kk + 1) * 32);
      nb = *(const f32x4*)(arow + (kk + 1) * 32 + 4);
    }
    bf16x8 af = cvt8v(pa, pb);
    const ushort* bp = Bw + kk * (DD * 32) + boff;
#pragma unroll
    for (int nt = 0; nt < 16; ++nt) {
      bf16x8 bfr = *(const bf16x8*)(bp + nt * 512);
      acc[nt] = __builtin_amdgcn_mfma_f32_16x16x32_bf16(af, bfr, acc[nt], 0, 0, 0);
    }
    pa = na; pb = nb;
  }

  __shared__ ushort lt[256][72];
#pragma unroll
  for (int nt = 0; nt < 16; ++nt) {
    int nl = nt * 16 + lr;
    float bv = bias[n0 + nl];
#pragma unroll
    for (int r = 0; r < 4; ++r)
      lt[nl][w * 16 + lh * 4 + r] = f2bf(acc[nt][r] + bv);
  }
  __syncthreads();
  const int bb = m0 >> 11;
  const int s0 = m0 & 2047;
  for (int i = tid; i < 256 * 64; i += 256) {
    int nn = i >> 6, mm = i & 63;
    int d = n0 + nn, t = s0 + mm;
    Vp[((size_t)(bb * 64 + (t >> 5)) * DD + d) * 32 + (t & 31)] = lt[nn][mm];
  }
}

// ---- pass 1: S = QK^T (split-bf16), fixed-shift exp, P~ = e*mask (bf16, k-packed),
//      Z row-sums via atomicAdd. 128x128 tile, 8 waves, NO block-wide softmax sync.
__global__ __launch_bounds__(512, 4)
void gemm_s(const ushort* __restrict__ Qph, const ushort* __restrict__ Qpl,
            const ushort* __restrict__ Kph, const ushort* __restrict__ Kpl,
            const float* __restrict__ isc, const float* __restrict__ dmask,
            ushort* __restrict__ Pp, float* __restrict__ Z)
{
  const int bid = blockIdx.x;
  const int bb = bid & 7;                 // batch <-> XCD affinity
  const int tt = bid >> 3;
  const int m0 = (tt & 15) * 128;
  const int n0 = (tt >> 4) * 128;
  const int tid = threadIdx.x;
  const int w  = tid >> 6;
  const int l  = tid & 63;
  const int lr = l & 15;
  const int lh = l >> 4;
  const int wm = w & 3;                   // 4 m-groups of 32 rows
  const int wn = w >> 2;                  // 2 n-groups of 64 cols

  const size_t base = (size_t)(bb * 7) * SS * 32;
  const ushort* qh = Qph + base + (size_t)(m0 + wm * 32 + lr) * 32 + lh * 8;
  const ushort* ql = Qpl + base + (size_t)(m0 + wm * 32 + lr) * 32 + lh * 8;
  const ushort* kh = Kph + base + (size_t)(n0 + wn * 64 + lr) * 32 + lh * 8;
  const ushort* kl = Kpl + base + (size_t)(n0 + wn * 64 + lr) * 32 + lh * 8;

  const f32x4 fzero = {0.f, 0.f, 0.f, 0.f};
  f32x4 acc[2][4];
#pragma unroll
  for (int mf = 0; mf < 2; ++mf)
#pragma unroll
    for (int nf = 0; nf < 4; ++nf) acc[mf][nf] = fzero;

#pragma unroll 1
  for (int kk = 0; kk < 7; ++kk) {
    const size_t ko = (size_t)kk * (SS * 32);
    bf16x8 ah[2], al[2];
#pragma unroll
    for (int mf = 0; mf < 2; ++mf) {
      ah[mf] = *(const bf16x8*)(qh + ko + mf * 512);
      al[mf] = *(const bf16x8*)(ql + ko + mf * 512);
    }
#pragma unroll
    for (int nf = 0; nf < 4; ++nf) {
      bf16x8 bh = *(const bf16x8*)(kh + ko + nf * 512);
      bf16x8 bl = *(const bf16x8*)(kl + ko + nf * 512);
#pragma unroll
      for (int mf = 0; mf < 2; ++mf) {
        acc[mf][nf] = __builtin_amdgcn_mfma_f32_16x16x32_bf16(ah[mf], bh, acc[mf][nf], 0, 0, 0);
        acc[mf][nf] = __builtin_amdgcn_mfma_f32_16x16x32_bf16(ah[mf], bl, acc[mf][nf], 0, 0, 0);
        acc[mf][nf] = __builtin_amdgcn_mfma_f32_16x16x32_bf16(al[mf], bh, acc[mf][nf], 0, 0, 0);
      }
    }
  }

  // epilogue: scale, exp(.-MSHIFT), Z partial sums (atomic), P~ store (packed bf16)
#pragma unroll
  for (int mf = 0; mf < 2; ++mf) {
#pragma unroll
    for (int r = 0; r < 4; ++r) {
      const int sr = m0 + wm * 32 + mf * 16 + lh * 4 + r;   // batch-local s row
      float z = 0.f;
#pragma unroll
      for (int nf = 0; nf < 4; ++nf) {
        const int tc = n0 + wn * 64 + nf * 16 + lr;
        float iv = isc[(size_t)sr * SS + tc];
        float sval = acc[mf][nf][r] * __builtin_amdgcn_rcpf(iv);
        float e = __expf(sval - MSHIFT);
        z += e;
        float mk = dmask[(size_t)bb * SS * SS + (size_t)sr * SS + tc];
        Pp[((size_t)(bb * 64 + (tc >> 5)) * SS + sr) * 32 + (tc & 31)] = f2bf(e * mk);
      }
#pragma unroll
      for (int off = 1; off < 16; off <<= 1) z += __shfl_xor(z, off);
      if (lr == 0) atomicAdd(&Z[bb * SS + sr], z);
    }
  }
}

// ---- pass 2: O = (P~ V) / Z. 128x128 tile, 8 waves, plain bf16 GEMM, k=2048 ----
__global__ __launch_bounds__(512, 4)
void gemm_pv(const ushort* __restrict__ Pp, const ushort* __restrict__ Vp,
             const float* __restrict__ Z, float* __restrict__ out)
{
  const int bid = blockIdx.x;
  const int bb = bid & 7;                 // batch <-> XCD affinity
  const int tt = bid >> 3;                // 0..95
  const int m0 = (tt & 15) * 128;         // s rows
  const int n0 = (tt >> 4) * 128;         // d cols (6 groups)
  const int tid = threadIdx.x;
  const int w  = tid >> 6;
  const int l  = tid & 63;
  const int lr = l & 15;
  const int lh = l >> 4;
  const int wm = w & 3;
  const int wn = w >> 2;

  const ushort* pa = Pp + (size_t)(bb * 64) * (SS * 32) + (size_t)(m0 + wm * 32 + lr) * 32 + lh * 8;
  const ushort* vb = Vp + (size_t)(bb * 64) * (DD * 32) + (size_t)(n0 + wn * 64 + lr) * 32 + lh * 8;

  const f32x4 fzero = {0.f, 0.f, 0.f, 0.f};
  f32x4 acc[2][4];
#pragma unroll
  for (int mf = 0; mf < 2; ++mf)
#pragma unroll
    for (int nf = 0; nf < 4; ++nf) acc[mf][nf] = fzero;

#pragma unroll 2
  for (int kk = 0; kk < 64; ++kk) {
    const size_t po = (size_t)kk * (SS * 32);
    const size_t vo = (size_t)kk * (DD * 32);
    bf16x8 af[2];
#pragma unroll
    for (int mf = 0; mf < 2; ++mf) af[mf] = *(const bf16x8*)(pa + po + mf * 512);
#pragma unroll
    for (int nf = 0; nf < 4; ++nf) {
      bf16x8 bfr = *(const bf16x8*)(vb + vo + nf * 512);
#pragma unroll
      for (int mf = 0; mf < 2; ++mf)
        acc[mf][nf] = __builtin_amdgcn_mfma_f32_16x16x32_bf16(af[mf], bfr, acc[mf][nf], 0, 0, 0);
    }
  }

#pragma unroll
  for (int mf = 0; mf < 2; ++mf) {
#pragma unroll
    for (int r = 0; r < 4; ++r) {
      const int sr = m0 + wm * 32 + mf * 16 + lh * 4 + r;
      float rz = __builtin_amdgcn_rcpf(Z[bb * SS + sr]);
#pragma unroll
      for (int nf = 0; nf < 4; ++nf) {
        const int dc = n0 + wn * 64 + nf * 16 + lr;
        out[((size_t)bb * SS + sr) * DD + dc] = acc[mf][nf][r] * rz;
      }
    }
  }
}

extern "C" void kernel_launch(void* const* d_in, const int* in_sizes, int n_in,
                              void* d_out, int out_size, void* d_ws, size_t ws_size,
                              hipStream_t stream) {
  const float* x1  = (const float*)d_in[0];
  const float* x2  = (const float*)d_in[1];
  const float* x3  = (const float*)d_in[2];
  const float* Wq  = (const float*)d_in[3];
  const float* bq  = (const float*)d_in[4];
  const float* Wk  = (const float*)d_in[5];
  const float* bk  = (const float*)d_in[6];
  const float* Wv  = (const float*)d_in[7];
  const float* bv  = (const float*)d_in[8];
  const float* isc = (const float*)d_in[9];
  const float* dmk = (const float*)d_in[10];
  float* out = (float*)d_out;

  const size_t QKN = (size_t)NB * 7 * SS * 32;        // 3,670,016
  const size_t VPN = (size_t)NB * 64 * DD * 32;       // 12,582,912
  const size_t WN  = (size_t)WROWS * DD;              // 196,608
  const size_t NV  = (size_t)DD * DD;                 // 589,824
  const size_t PPN = (size_t)NB * 64 * SS * 32;       // 33,554,432

  ushort* Qph = (ushort*)d_ws;
  ushort* Qpl = Qph + QKN;
  ushort* Kph = Qpl + QKN;
  ushort* Kpl = Kph + QKN;
  ushort* Vp  = Kpl + QKN;
  ushort* Wqh = Vp + VPN;
  ushort* Wql = Wqh + WN;
  ushort* Wkh = Wql + WN;
  ushort* Wkl = Wkh + WN;
  ushort* Wvb = Wkl + WN;
  ushort* Pp  = Wvb + NV;
  float*  Zb  = (float*)(Pp + PPN);                   // [8][2048] f32

  dim3 blk(256);
  prep_w<<<dim3(512), blk, 0, stream>>>(Wq, Wk, Wv, Wqh, Wql, Wkh, Wkl, Wvb, Zb);
  gemm_qk<<<dim3(256, 4), blk, 0, stream>>>(x1, x2, Wqh, Wql, Wkh, Wkl, bq, bk,
                                            Qph, Qpl, Kph, Kpl);
  gemm_v <<<dim3(256, 3), blk, 0, stream>>>(x3, Wvb, bv, Vp);
  gemm_s <<<dim3(2048), dim3(512), 0, stream>>>(Qph, Qpl, Kph, Kpl, isc, dmk, Pp, Zb);
  gemm_pv<<<dim3(768),  dim3(512), 0, stream>>>(Pp, Vp, Zb, out);
}

// Round 10
// 397.358 us; speedup vs baseline: 1.7839x; 1.2890x over previous
//
#include <hip/hip_runtime.h>
#include <hip/hip_bf16.h>

typedef unsigned short ushort;
typedef short bf16x8 __attribute__((ext_vector_type(8)));
typedef float f32x4 __attribute__((ext_vector_type(4)));

#define NB 8
#define SS 2048
#define DD 768
#define DKV 214
#define DKP 224
#define WROWS 256
#define MSHIFT 40.0f

__device__ __forceinline__ float bf2f(ushort u) {
  union { unsigned int i; float f; } v; v.i = ((unsigned int)u) << 16; return v.f;
}
__device__ __forceinline__ ushort f2bf(float f) {
  union { float f; unsigned int i; } v; v.f = f;
  unsigned int x = v.i;
  return (ushort)((x + 0x7fffu + ((x >> 16) & 1u)) >> 16);
}
__device__ __forceinline__ void split8v(f32x4 a, f32x4 b, bf16x8& h, bf16x8& l) {
#pragma unroll
  for (int j = 0; j < 4; ++j) {
    ushort h0 = f2bf(a[j]); h[j]     = (short)h0; l[j]     = (short)f2bf(a[j] - bf2f(h0));
    ushort h1 = f2bf(b[j]); h[j + 4] = (short)h1; l[j + 4] = (short)f2bf(b[j] - bf2f(h1));
  }
}
__device__ __forceinline__ bf16x8 cvt8v(f32x4 a, f32x4 b) {
  bf16x8 r;
#pragma unroll
  for (int j = 0; j < 4; ++j) { r[j] = (short)f2bf(a[j]); r[j + 4] = (short)f2bf(b[j]); }
  return r;
}
// async global->LDS, 16B per lane; LDS dest is wave-uniform base + lane*16
__device__ __forceinline__ void gload16(const void* g, void* l) {
  __builtin_amdgcn_global_load_lds(
      (const __attribute__((address_space(1))) void*)g,
      (__attribute__((address_space(3))) void*)l, 16, 0, 0);
}

// ---- weight prep + Z zero. Wq,Wk -> k-packed [24][256][32] hi/lo; Wv -> [24][768][32] ----
__global__ __launch_bounds__(256)
void prep_w(const float* __restrict__ Wq, const float* __restrict__ Wk,
            const float* __restrict__ Wv,
            ushort* __restrict__ Wqh, ushort* __restrict__ Wql,
            ushort* __restrict__ Wkh, ushort* __restrict__ Wkl,
            ushort* __restrict__ Wvb, float* __restrict__ Z)
{
  const int NW = WROWS * DD;
  const int NV = DD * DD;
  for (int i = blockIdx.x * 256 + threadIdx.x; i < NB * SS; i += gridDim.x * 256)
    Z[i] = 0.f;
  for (int i = blockIdx.x * 256 + threadIdx.x; i < 2 * NW + NV; i += gridDim.x * 256) {
    if (i < NW) {
      int r = i / DD, c = i % DD;
      float v = (r < DKV) ? Wq[i] : 0.f;
      ushort h = f2bf(v);
      int d = (c >> 5) * (WROWS * 32) + r * 32 + (c & 31);
      Wqh[d] = h; Wql[d] = f2bf(v - bf2f(h));
    } else if (i < 2 * NW) {
      int j = i - NW;
      int r = j / DD, c = j % DD;
      float v = (r < DKV) ? Wk[j] : 0.f;
      ushort h = f2bf(v);
      int d = (c >> 5) * (WROWS * 32) + r * 32 + (c & 31);
      Wkh[d] = h; Wkl[d] = f2bf(v - bf2f(h));
    } else {
      int j = i - 2 * NW;
      int r = j / DD, c = j % DD;
      Wvb[(c >> 5) * (DD * 32) + r * 32 + (c & 31)] = f2bf(Wv[j]);
    }
  }
}

// ---- fused Q+K projection -> k-packed hi/lo [b][7][2048][32] ----
__global__ __launch_bounds__(256, 4)
void gemm_qk(const float* __restrict__ x1, const float* __restrict__ x2,
             const ushort* __restrict__ Wqh, const ushort* __restrict__ Wql,
             const ushort* __restrict__ Wkh, const ushort* __restrict__ Wkl,
             const float* __restrict__ bq, const float* __restrict__ bk,
             ushort* __restrict__ Qph, ushort* __restrict__ Qpl,
             ushort* __restrict__ Kph, ushort* __restrict__ Kpl)
{
  const int m0 = blockIdx.x * 64;
  const int which = blockIdx.y >> 1;
  const int n0 = (blockIdx.y & 1) * 128;
  const int tid = threadIdx.x;
  const int w  = tid >> 6;
  const int l  = tid & 63;
  const int lr = l & 15;
  const int lh = l >> 4;

  const float*  A    = which ? x2 : x1;
  const ushort* Bh   = which ? Wkh : Wqh;
  const ushort* Bl   = which ? Wkl : Wql;
  const float*  bias = which ? bk : bq;
  ushort* Ch = which ? Kph : Qph;
  ushort* Cl = which ? Kpl : Qpl;

  const f32x4 fzero = {0.f, 0.f, 0.f, 0.f};
  f32x4 acc[8];
#pragma unroll
  for (int nt = 0; nt < 8; ++nt) acc[nt] = fzero;

  const float* arow = A + (size_t)(m0 + w * 16 + lr) * DD + lh * 8;
  const int boff = (n0 + lr) * 32 + lh * 8;

  f32x4 pa = *(const f32x4*)(arow);
  f32x4 pb = *(const f32x4*)(arow + 4);
  for (int kk = 0; kk < 24; ++kk) {
    f32x4 na = fzero, nb = fzero;
    if (kk < 23) {
      na = *(const f32x4*)(arow + (kk + 1) * 32);
      nb = *(const f32x4*)(arow + (kk + 1) * 32 + 4);
    }
    bf16x8 ah, al; split8v(pa, pb, ah, al);
    const ushort* bhp = Bh + kk * (WROWS * 32) + boff;
    const ushort* blp = Bl + kk * (WROWS * 32) + boff;
#pragma unroll
    for (int nt = 0; nt < 8; ++nt) {
      bf16x8 wh = *(const bf16x8*)(bhp + nt * 512);
      bf16x8 wl = *(const bf16x8*)(blp + nt * 512);
      acc[nt] = __builtin_amdgcn_mfma_f32_16x16x32_bf16(ah, wh, acc[nt], 0, 0, 0);
      acc[nt] = __builtin_amdgcn_mfma_f32_16x16x32_bf16(ah, wl, acc[nt], 0, 0, 0);
      acc[nt] = __builtin_amdgcn_mfma_f32_16x16x32_bf16(al, wh, acc[nt], 0, 0, 0);
    }
    pa = na; pb = nb;
  }

#pragma unroll
  for (int nt = 0; nt < 8; ++nt) {
    int n = n0 + nt * 16 + lr;
    if (n >= DKP) continue;
    float bv = (n < DKV) ? bias[n] : 0.f;
#pragma unroll
    for (int r = 0; r < 4; ++r) {
      int m = m0 + w * 16 + lh * 4 + r;
      int bb = m >> 11, s = m & 2047;
      float val = (n < DKV) ? (acc[nt][r] + bv) : 0.f;
      ushort h = f2bf(val);
      size_t idx = ((size_t)(bb * 7 + (n >> 5)) * SS + s) * 32 + (n & 31);
      Ch[idx] = h;
      Cl[idx] = f2bf(val - bf2f(h));
    }
  }
}

// ---- V projection -> k-packed Vp[b][64][768][32] ----
__global__ __launch_bounds__(256, 3)
void gemm_v(const float* __restrict__ A, const ushort* __restrict__ Bw,
            const float* __restrict__ bias, ushort* __restrict__ Vp)
{
  const int m0 = blockIdx.x * 64;
  const int n0 = blockIdx.y * 256;
  const int tid = threadIdx.x;
  const int w  = tid >> 6;
  const int l  = tid & 63;
  const int lr = l & 15;
  const int lh = l >> 4;

  const f32x4 fzero = {0.f, 0.f, 0.f, 0.f};
  f32x4 acc[16];
#pragma unroll
  for (int nt = 0; nt < 16; ++nt) acc[nt] = fzero;

  const float* arow = A + (size_t)(m0 + w * 16 + lr) * DD + lh * 8;
  const int boff = (n0 + lr) * 32 + lh * 8;

  f32x4 pa = *(const f32x4*)(arow);
  f32x4 pb = *(const f32x4*)(arow + 4);
  for (int kk = 0; kk < 24; ++kk) {
    f32x4 na = fzero, nb = fzero;
    if (kk < 23) {
      na = *(const f32x4*)(arow + (kk + 1) * 32);
      nb = *(const f32x4*)(arow + (kk + 1) * 32 + 4);
    }
    bf16x8 af = cvt8v(pa, pb);
    const ushort* bp = Bw + kk * (DD * 32) + boff;
#pragma unroll
    for (int nt = 0; nt < 16; ++nt) {
      bf16x8 bfr = *(const bf16x8*)(bp + nt * 512);
      acc[nt] = __builtin_amdgcn_mfma_f32_16x16x32_bf16(af, bfr, acc[nt], 0, 0, 0);
    }
    pa = na; pb = nb;
  }

  __shared__ ushort lt[256][72];
#pragma unroll
  for (int nt = 0; nt < 16; ++nt) {
    int nl = nt * 16 + lr;
    float bv = bias[n0 + nl];
#pragma unroll
    for (int r = 0; r < 4; ++r)
      lt[nl][w * 16 + lh * 4 + r] = f2bf(acc[nt][r] + bv);
  }
  __syncthreads();
  const int bb = m0 >> 11;
  const int s0 = m0 & 2047;
  for (int i = tid; i < 256 * 64; i += 256) {
    int nn = i >> 6, mm = i & 63;
    int d = n0 + nn, t = s0 + mm;
    Vp[((size_t)(bb * 64 + (t >> 5)) * DD + d) * 32 + (t & 31)] = lt[nn][mm];
  }
}

// ---- pass 1: S = QK^T (split-bf16), 2-phase LDS pipeline, fixed-shift exp,
//      P~ = e*mask (bf16, k-packed), Z row-sums via atomicAdd.
// LDS [dbuf][qh,ql,kh,kl][128 rows][64B] = 64 KB. Swizzle: slot ^= (row>>1)&3
// applied on the GLOBAL source (write-linear LDS) and on reads (rule #21).
__global__ __launch_bounds__(512, 4)
void gemm_s(const ushort* __restrict__ Qph, const ushort* __restrict__ Qpl,
            const ushort* __restrict__ Kph, const ushort* __restrict__ Kpl,
            const float* __restrict__ isc, const float* __restrict__ dmask,
            ushort* __restrict__ Pp, float* __restrict__ Z)
{
  const int bid = blockIdx.x;
  const int bb = bid & 7;
  const int tt = bid >> 3;
  const int m0 = (tt & 15) * 128;
  const int n0 = (tt >> 4) * 128;
  const int tid = threadIdx.x;
  const int w  = tid >> 6;
  const int l  = tid & 63;
  const int lr = l & 15;
  const int lh = l >> 4;
  const int wm = w & 3;
  const int wn = w >> 2;

  __shared__ __align__(16) char lds[2][4][128][64];   // 64 KB

  // staging geometry: wave w stages rows w*16..+15 (1KB) of each 8KB chunk
  const int srow = (w << 4) + (l >> 2);
  const int ssl  = l & 3;
  const size_t gc = (size_t)srow * 64 + (size_t)((ssl ^ ((srow >> 1) & 3)) << 4);

  const char* gqh = (const char*)Qph + ((size_t)(bb * 7) * SS + m0) * 64;
  const char* gql = (const char*)Qpl + ((size_t)(bb * 7) * SS + m0) * 64;
  const char* gkh = (const char*)Kph + ((size_t)(bb * 7) * SS + n0) * 64;
  const char* gkl = (const char*)Kpl + ((size_t)(bb * 7) * SS + n0) * 64;

  const f32x4 fzero = {0.f, 0.f, 0.f, 0.f};
  f32x4 acc[2][4];
#pragma unroll
  for (int mf = 0; mf < 2; ++mf)
#pragma unroll
    for (int nf = 0; nf < 4; ++nf) acc[mf][nf] = fzero;

#define SSTAGE(buf, kk) do {                                            \
    size_t ko = (size_t)(kk) * (SS * 64);                               \
    gload16(gqh + ko + gc, &lds[buf][0][w << 4][0]);                    \
    gload16(gql + ko + gc, &lds[buf][1][w << 4][0]);                    \
    gload16(gkh + ko + gc, &lds[buf][2][w << 4][0]);                    \
    gload16(gkl + ko + gc, &lds[buf][3][w << 4][0]);                    \
  } while (0)

  SSTAGE(0, 0);
  __syncthreads();
#pragma unroll
  for (int t = 0; t < 7; ++t) {
    const int buf = t & 1;
    if (t < 6) SSTAGE(buf ^ 1, t + 1);
    bf16x8 ah[2], al[2];
#pragma unroll
    for (int mf = 0; mf < 2; ++mf) {
      int ar = wm * 32 + mf * 16 + lr;
      int ao = (lh ^ ((ar >> 1) & 3)) << 4;
      ah[mf] = *(const bf16x8*)&lds[buf][0][ar][ao];
      al[mf] = *(const bf16x8*)&lds[buf][1][ar][ao];
    }
#pragma unroll
    for (int nf = 0; nf < 4; ++nf) {
      int br = wn * 64 + nf * 16 + lr;
      int bo = (lh ^ ((br >> 1) & 3)) << 4;
      bf16x8 bh = *(const bf16x8*)&lds[buf][2][br][bo];
      bf16x8 bl = *(const bf16x8*)&lds[buf][3][br][bo];
#pragma unroll
      for (int mf = 0; mf < 2; ++mf) {
        acc[mf][nf] = __builtin_amdgcn_mfma_f32_16x16x32_bf16(ah[mf], bh, acc[mf][nf], 0, 0, 0);
        acc[mf][nf] = __builtin_amdgcn_mfma_f32_16x16x32_bf16(ah[mf], bl, acc[mf][nf], 0, 0, 0);
        acc[mf][nf] = __builtin_amdgcn_mfma_f32_16x16x32_bf16(al[mf], bh, acc[mf][nf], 0, 0, 0);
      }
    }
    __syncthreads();
  }
#undef SSTAGE

  // epilogue: scale, exp(.-MSHIFT), Z partial sums (atomic), P~ store (packed bf16)
#pragma unroll
  for (int mf = 0; mf < 2; ++mf) {
#pragma unroll
    for (int r = 0; r < 4; ++r) {
      const int sr = m0 + wm * 32 + mf * 16 + lh * 4 + r;
      float z = 0.f;
#pragma unroll
      for (int nf = 0; nf < 4; ++nf) {
        const int tc = n0 + wn * 64 + nf * 16 + lr;
        float iv = isc[(size_t)sr * SS + tc];
        float sval = acc[mf][nf][r] * __builtin_amdgcn_rcpf(iv);
        float e = __expf(sval - MSHIFT);
        z += e;
        float mk = dmask[(size_t)bb * SS * SS + (size_t)sr * SS + tc];
        Pp[((size_t)(bb * 64 + (tc >> 5)) * SS + sr) * 32 + (tc & 31)] = f2bf(e * mk);
      }
#pragma unroll
      for (int off = 1; off < 16; off <<= 1) z += __shfl_xor(z, off);
      if (lr == 0) atomicAdd(&Z[bb * SS + sr], z);
    }
  }
}

// ---- pass 2: O = (P~ V) / Z. 2-phase LDS pipeline, k=2048 (32 steps of 64).
// LDS [dbuf][P,V][pack0/1][128 rows][64B] = 64 KB. Same swizzle discipline.
__global__ __launch_bounds__(512, 4)
void gemm_pv(const ushort* __restrict__ Pp, const ushort* __restrict__ Vp,
             const float* __restrict__ Z, float* __restrict__ out)
{
  const int bid = blockIdx.x;
  const int bb = bid & 7;
  const int tt = bid >> 3;
  const int m0 = (tt & 15) * 128;
  const int n0 = (tt >> 4) * 128;
  const int tid = threadIdx.x;
  const int w  = tid >> 6;
  const int l  = tid & 63;
  const int lr = l & 15;
  const int lh = l >> 4;
  const int wm = w & 3;
  const int wn = w >> 2;

  __shared__ __align__(16) char lds[2][2][2][128][64];   // 64 KB

  const int srow = (w << 4) + (l >> 2);
  const int ssl  = l & 3;
  const size_t gc = (size_t)srow * 64 + (size_t)((ssl ^ ((srow >> 1) & 3)) << 4);

  const char* gpb = (const char*)Pp + ((size_t)(bb * 64) * SS + m0) * 64;
  const char* gvb = (const char*)Vp + ((size_t)(bb * 64) * DD + n0) * 64;

  const f32x4 fzero = {0.f, 0.f, 0.f, 0.f};
  f32x4 acc[2][4];
#pragma unroll
  for (int mf = 0; mf < 2; ++mf)
#pragma unroll
    for (int nf = 0; nf < 4; ++nf) acc[mf][nf] = fzero;

#define PVSTAGE(buf, t) do {                                              \
    size_t k0 = (size_t)(t) * 2;                                          \
    gload16(gpb + k0 * (SS * 64) + gc,        &lds[buf][0][0][w << 4][0]); \
    gload16(gpb + (k0 + 1) * (SS * 64) + gc,  &lds[buf][0][1][w << 4][0]); \
    gload16(gvb + k0 * (DD * 64) + gc,        &lds[buf][1][0][w << 4][0]); \
    gload16(gvb + (k0 + 1) * (DD * 64) + gc,  &lds[buf][1][1][w << 4][0]); \
  } while (0)

  PVSTAGE(0, 0);
  __syncthreads();
  for (int t = 0; t < 32; ++t) {
    const int buf = t & 1;
    if (t < 31) PVSTAGE(buf ^ 1, t + 1);
#pragma unroll
    for (int pk = 0; pk < 2; ++pk) {
      bf16x8 af[2];
#pragma unroll
      for (int mf = 0; mf < 2; ++mf) {
        int ar = wm * 32 + mf * 16 + lr;
        int ao = (lh ^ ((ar >> 1) & 3)) << 4;
        af[mf] = *(const bf16x8*)&lds[buf][0][pk][ar][ao];
      }
#pragma unroll
      for (int nf = 0; nf < 4; ++nf) {
        int br = wn * 64 + nf * 16 + lr;
        int bo = (lh ^ ((br >> 1) & 3)) << 4;
        bf16x8 bfr = *(const bf16x8*)&lds[buf][1][pk][br][bo];
#pragma unroll
        for (int mf = 0; mf < 2; ++mf)
          acc[mf][nf] = __builtin_amdgcn_mfma_f32_16x16x32_bf16(af[mf], bfr, acc[mf][nf], 0, 0, 0);
      }
    }
    __syncthreads();
  }
#undef PVSTAGE

#pragma unroll
  for (int mf = 0; mf < 2; ++mf) {
#pragma unroll
    for (int r = 0; r < 4; ++r) {
      const int sr = m0 + wm * 32 + mf * 16 + lh * 4 + r;
      float rz = __builtin_amdgcn_rcpf(Z[bb * SS + sr]);
#pragma unroll
      for (int nf = 0; nf < 4; ++nf) {
        const int dc = n0 + wn * 64 + nf * 16 + lr;
        out[((size_t)bb * SS + sr) * DD + dc] = acc[mf][nf][r] * rz;
      }
    }
  }
}

extern "C" void kernel_launch(void* const* d_in, const int* in_sizes, int n_in,
                              void* d_out, int out_size, void* d_ws, size_t ws_size,
                              hipStream_t stream) {
  const float* x1  = (const float*)d_in[0];
  const float* x2  = (const float*)d_in[1];
  const float* x3  = (const float*)d_in[2];
  const float* Wq  = (const float*)d_in[3];
  const float* bq  = (const float*)d_in[4];
  const float* Wk  = (const float*)d_in[5];
  const float* bk  = (const float*)d_in[6];
  const float* Wv  = (const float*)d_in[7];
  const float* bv  = (const float*)d_in[8];
  const float* isc = (const float*)d_in[9];
  const float* dmk = (const float*)d_in[10];
  float* out = (float*)d_out;

  const size_t QKN = (size_t)NB * 7 * SS * 32;
  const size_t VPN = (size_t)NB * 64 * DD * 32;
  const size_t WN  = (size_t)WROWS * DD;
  const size_t NV  = (size_t)DD * DD;
  const size_t PPN = (size_t)NB * 64 * SS * 32;

  ushort* Qph = (ushort*)d_ws;
  ushort* Qpl = Qph + QKN;
  ushort* Kph = Qpl + QKN;
  ushort* Kpl = Kph + QKN;
  ushort* Vp  = Kpl + QKN;
  ushort* Wqh = Vp + VPN;
  ushort* Wql = Wqh + WN;
  ushort* Wkh = Wql + WN;
  ushort* Wkl = Wkh + WN;
  ushort* Wvb = Wkl + WN;
  ushort* Pp  = Wvb + NV;
  float*  Zb  = (float*)(Pp + PPN);

  dim3 blk(256);
  prep_w<<<dim3(512), blk, 0, stream>>>(Wq, Wk, Wv, Wqh, Wql, Wkh, Wkl, Wvb, Zb);
  gemm_qk<<<dim3(256, 4), blk, 0, stream>>>(x1, x2, Wqh, Wql, Wkh, Wkl, bq, bk,
                                            Qph, Qpl, Kph, Kpl);
  gemm_v <<<dim3(256, 3), blk, 0, stream>>>(x3, Wvb, bv, Vp);
  gemm_s <<<dim3(2048), dim3(512), 0, stream>>>(Qph, Qpl, Kph, Kpl, isc, dmk, Pp, Zb);
  gemm_pv<<<dim3(768),  dim3(512), 0, stream>>>(Pp, Vp, Zb, out);
}

// Round 11
// 283.458 us; speedup vs baseline: 2.5007x; 1.4018x over previous
//
#include <hip/hip_runtime.h>
#include <hip/hip_bf16.h>

typedef unsigned short ushort;
typedef short bf16x8 __attribute__((ext_vector_type(8)));
typedef float f32x4 __attribute__((ext_vector_type(4)));

#define NB 8
#define SS 2048
#define DD 768
#define DKV 214
#define DKP 224
#define WROWS 256
#define MSHIFT 40.0f

__device__ __forceinline__ float bf2f(ushort u) {
  union { unsigned int i; float f; } v; v.i = ((unsigned int)u) << 16; return v.f;
}
__device__ __forceinline__ ushort f2bf(float f) {
  union { float f; unsigned int i; } v; v.f = f;
  unsigned int x = v.i;
  return (ushort)((x + 0x7fffu + ((x >> 16) & 1u)) >> 16);
}
__device__ __forceinline__ void split8v(f32x4 a, f32x4 b, bf16x8& h, bf16x8& l) {
#pragma unroll
  for (int j = 0; j < 4; ++j) {
    ushort h0 = f2bf(a[j]); h[j]     = (short)h0; l[j]     = (short)f2bf(a[j] - bf2f(h0));
    ushort h1 = f2bf(b[j]); h[j + 4] = (short)h1; l[j + 4] = (short)f2bf(b[j] - bf2f(h1));
  }
}
__device__ __forceinline__ bf16x8 cvt8v(f32x4 a, f32x4 b) {
  bf16x8 r;
#pragma unroll
  for (int j = 0; j < 4; ++j) { r[j] = (short)f2bf(a[j]); r[j + 4] = (short)f2bf(b[j]); }
  return r;
}
// async global->LDS, 16B per lane; LDS dest is wave-uniform base + lane*16
__device__ __forceinline__ void gload16(const void* g, void* l) {
  __builtin_amdgcn_global_load_lds(
      (const __attribute__((address_space(1))) void*)g,
      (__attribute__((address_space(3))) void*)l, 16, 0, 0);
}

// ---- weight prep + Z zero. Wq,Wk -> k-packed [24][256][32] hi/lo; Wv -> [24][768][32] ----
__global__ __launch_bounds__(256)
void prep_w(const float* __restrict__ Wq, const float* __restrict__ Wk,
            const float* __restrict__ Wv,
            ushort* __restrict__ Wqh, ushort* __restrict__ Wql,
            ushort* __restrict__ Wkh, ushort* __restrict__ Wkl,
            ushort* __restrict__ Wvb, float* __restrict__ Z)
{
  const int NW = WROWS * DD;
  const int NV = DD * DD;
  for (int i = blockIdx.x * 256 + threadIdx.x; i < NB * SS; i += gridDim.x * 256)
    Z[i] = 0.f;
  for (int i = blockIdx.x * 256 + threadIdx.x; i < 2 * NW + NV; i += gridDim.x * 256) {
    if (i < NW) {
      int r = i / DD, c = i % DD;
      float v = (r < DKV) ? Wq[i] : 0.f;
      ushort h = f2bf(v);
      int d = (c >> 5) * (WROWS * 32) + r * 32 + (c & 31);
      Wqh[d] = h; Wql[d] = f2bf(v - bf2f(h));
    } else if (i < 2 * NW) {
      int j = i - NW;
      int r = j / DD, c = j % DD;
      float v = (r < DKV) ? Wk[j] : 0.f;
      ushort h = f2bf(v);
      int d = (c >> 5) * (WROWS * 32) + r * 32 + (c & 31);
      Wkh[d] = h; Wkl[d] = f2bf(v - bf2f(h));
    } else {
      int j = i - 2 * NW;
      int r = j / DD, c = j % DD;
      Wvb[(c >> 5) * (DD * 32) + r * 32 + (c & 31)] = f2bf(Wv[j]);
    }
  }
}

// ---- fused Q+K projection -> k-packed hi/lo [b][7][2048][32].
// B (pre-split weights) double-buffered in LDS via global_load_lds; A direct f32
// + in-reg split (each element split once per block). Swizzle: slot ^= (row>>1)&3
// on global source and on reads (write-linear LDS, rule #21).
__global__ __launch_bounds__(256, 4)
void gemm_qk(const float* __restrict__ x1, const float* __restrict__ x2,
             const ushort* __restrict__ Wqh, const ushort* __restrict__ Wql,
             const ushort* __restrict__ Wkh, const ushort* __restrict__ Wkl,
             const float* __restrict__ bq, const float* __restrict__ bk,
             ushort* __restrict__ Qph, ushort* __restrict__ Qpl,
             ushort* __restrict__ Kph, ushort* __restrict__ Kpl)
{
  const int m0 = blockIdx.x * 64;
  const int which = blockIdx.y >> 1;
  const int n0 = (blockIdx.y & 1) * 128;
  const int tid = threadIdx.x;
  const int w  = tid >> 6;
  const int l  = tid & 63;
  const int lr = l & 15;
  const int lh = l >> 4;

  const float*  A    = which ? x2 : x1;
  const ushort* Bh   = which ? Wkh : Wqh;
  const ushort* Bl   = which ? Wkl : Wql;
  const float*  bias = which ? bk : bq;
  ushort* Ch = which ? Kph : Qph;
  ushort* Cl = which ? Kpl : Qpl;

  __shared__ __align__(16) char lds[2][2][128][64];   // [dbuf][hi/lo][row][byte] 32 KB

  // staging: wave w stages rows w*16..+15 and +64 of each 8 KB half-tile
  const int srow = (w << 4) + (l >> 2);
  const size_t gc = (size_t)srow * 64 + (size_t)((((l & 3) ^ ((srow >> 1) & 3))) << 4);
  const char* gbh = (const char*)Bh + (size_t)n0 * 64;
  const char* gbl = (const char*)Bl + (size_t)n0 * 64;

  const f32x4 fzero = {0.f, 0.f, 0.f, 0.f};
  f32x4 acc[8];
#pragma unroll
  for (int nt = 0; nt < 8; ++nt) acc[nt] = fzero;

  const float* arow = A + (size_t)(m0 + w * 16 + lr) * DD + lh * 8;

#define QKSTAGE(buf, kk) do {                                             \
    size_t ko = (size_t)(kk) * (WROWS * 64);                              \
    gload16(gbh + ko + gc,        &lds[buf][0][w << 4][0]);               \
    gload16(gbh + ko + gc + 4096, &lds[buf][0][(w << 4) + 64][0]);        \
    gload16(gbl + ko + gc,        &lds[buf][1][w << 4][0]);               \
    gload16(gbl + ko + gc + 4096, &lds[buf][1][(w << 4) + 64][0]);        \
  } while (0)

  QKSTAGE(0, 0);
  f32x4 pa = *(const f32x4*)(arow);
  f32x4 pb = *(const f32x4*)(arow + 4);
  __syncthreads();

  for (int kk = 0; kk < 24; ++kk) {
    const int buf = kk & 1;
    if (kk < 23) QKSTAGE(buf ^ 1, kk + 1);
    f32x4 na = fzero, nb = fzero;
    if (kk < 23) {
      na = *(const f32x4*)(arow + (kk + 1) * 32);
      nb = *(const f32x4*)(arow + (kk + 1) * 32 + 4);
    }
    bf16x8 ah, al; split8v(pa, pb, ah, al);
#pragma unroll
    for (int nt = 0; nt < 8; ++nt) {
      int br = nt * 16 + lr;
      int bo = (lh ^ ((br >> 1) & 3)) << 4;
      bf16x8 wh = *(const bf16x8*)&lds[buf][0][br][bo];
      bf16x8 wl = *(const bf16x8*)&lds[buf][1][br][bo];
      acc[nt] = __builtin_amdgcn_mfma_f32_16x16x32_bf16(ah, wh, acc[nt], 0, 0, 0);
      acc[nt] = __builtin_amdgcn_mfma_f32_16x16x32_bf16(ah, wl, acc[nt], 0, 0, 0);
      acc[nt] = __builtin_amdgcn_mfma_f32_16x16x32_bf16(al, wh, acc[nt], 0, 0, 0);
    }
    __syncthreads();
    pa = na; pb = nb;
  }
#undef QKSTAGE

#pragma unroll
  for (int nt = 0; nt < 8; ++nt) {
    int n = n0 + nt * 16 + lr;
    if (n >= DKP) continue;
    float bv = (n < DKV) ? bias[n] : 0.f;
#pragma unroll
    for (int r = 0; r < 4; ++r) {
      int m = m0 + w * 16 + lh * 4 + r;
      int bb = m >> 11, s = m & 2047;
      float val = (n < DKV) ? (acc[nt][r] + bv) : 0.f;
      ushort h = f2bf(val);
      size_t idx = ((size_t)(bb * 7 + (n >> 5)) * SS + s) * 32 + (n & 31);
      Ch[idx] = h;
      Cl[idx] = f2bf(val - bf2f(h));
    }
  }
}

// ---- V projection -> k-packed Vp[b][64][768][32]. B staged in LDS (dbuf),
// A direct f32 + cvt. Staging LDS union'd with the transpose buffer.
__global__ __launch_bounds__(256, 3)
void gemm_v(const float* __restrict__ A, const ushort* __restrict__ Bw,
            const float* __restrict__ bias, ushort* __restrict__ Vp)
{
  const int m0 = blockIdx.x * 64;
  const int n0 = blockIdx.y * 256;
  const int tid = threadIdx.x;
  const int w  = tid >> 6;
  const int l  = tid & 63;
  const int lr = l & 15;
  const int lh = l >> 4;

  __shared__ __align__(16) char smem[36864];          // max(stage 32KB, lt 36KB)
  typedef char VBuf[256][64];
  VBuf* stage = (VBuf*)smem;                          // stage[2][256][64]
  ushort (*lt)[72] = (ushort(*)[72])smem;             // lt[256][72]

  const int srow = (w << 4) + (l >> 2);
  const size_t gc = (size_t)srow * 64 + (size_t)((((l & 3) ^ ((srow >> 1) & 3))) << 4);
  const char* gvw = (const char*)Bw + (size_t)n0 * 64;

  const f32x4 fzero = {0.f, 0.f, 0.f, 0.f};
  f32x4 acc[16];
#pragma unroll
  for (int nt = 0; nt < 16; ++nt) acc[nt] = fzero;

  const float* arow = A + (size_t)(m0 + w * 16 + lr) * DD + lh * 8;

#define VSTAGE(buf, kk) do {                                              \
    size_t ko = (size_t)(kk) * (DD * 64);                                 \
    gload16(gvw + ko + gc,         &stage[buf][w << 4][0]);               \
    gload16(gvw + ko + gc + 4096,  &stage[buf][(w << 4) + 64][0]);        \
    gload16(gvw + ko + gc + 8192,  &stage[buf][(w << 4) + 128][0]);       \
    gload16(gvw + ko + gc + 12288, &stage[buf][(w << 4) + 192][0]);       \
  } while (0)

  VSTAGE(0, 0);
  f32x4 pa = *(const f32x4*)(arow);
  f32x4 pb = *(const f32x4*)(arow + 4);
  __syncthreads();

  for (int kk = 0; kk < 24; ++kk) {
    const int buf = kk & 1;
    if (kk < 23) VSTAGE(buf ^ 1, kk + 1);
    f32x4 na = fzero, nb = fzero;
    if (kk < 23) {
      na = *(const f32x4*)(arow + (kk + 1) * 32);
      nb = *(const f32x4*)(arow + (kk + 1) * 32 + 4);
    }
    bf16x8 af = cvt8v(pa, pb);
#pragma unroll
    for (int nt = 0; nt < 16; ++nt) {
      int br = nt * 16 + lr;
      int bo = (lh ^ ((br >> 1) & 3)) << 4;
      bf16x8 bfr = *(const bf16x8*)&stage[buf][br][bo];
      acc[nt] = __builtin_amdgcn_mfma_f32_16x16x32_bf16(af, bfr, acc[nt], 0, 0, 0);
    }
    __syncthreads();
    pa = na; pb = nb;
  }
#undef VSTAGE

  // transpose epilogue (smem reuse; prior sync guarantees staging reads done)
#pragma unroll
  for (int nt = 0; nt < 16; ++nt) {
    int nl = nt * 16 + lr;
    float bv = bias[n0 + nl];
#pragma unroll
    for (int r = 0; r < 4; ++r)
      lt[nl][w * 16 + lh * 4 + r] = f2bf(acc[nt][r] + bv);
  }
  __syncthreads();
  const int bb = m0 >> 11;
  const int s0 = m0 & 2047;
  for (int i = tid; i < 256 * 64; i += 256) {
    int nn = i >> 6, mm = i & 63;
    int d = n0 + nn, t = s0 + mm;
    Vp[((size_t)(bb * 64 + (t >> 5)) * DD + d) * 32 + (t & 31)] = lt[nn][mm];
  }
}

// ---- pass 1: S = QK^T (split-bf16), 2-phase LDS pipeline, fixed-shift exp,
//      P~ = e*mask (bf16, k-packed), Z row-sums via atomicAdd.
__global__ __launch_bounds__(512, 4)
void gemm_s(const ushort* __restrict__ Qph, const ushort* __restrict__ Qpl,
            const ushort* __restrict__ Kph, const ushort* __restrict__ Kpl,
            const float* __restrict__ isc, const float* __restrict__ dmask,
            ushort* __restrict__ Pp, float* __restrict__ Z)
{
  const int bid = blockIdx.x;
  const int bb = bid & 7;
  const int tt = bid >> 3;
  const int m0 = (tt & 15) * 128;
  const int n0 = (tt >> 4) * 128;
  const int tid = threadIdx.x;
  const int w  = tid >> 6;
  const int l  = tid & 63;
  const int lr = l & 15;
  const int lh = l >> 4;
  const int wm = w & 3;
  const int wn = w >> 2;

  __shared__ __align__(16) char lds[2][4][128][64];   // 64 KB

  const int srow = (w << 4) + (l >> 2);
  const int ssl  = l & 3;
  const size_t gc = (size_t)srow * 64 + (size_t)((ssl ^ ((srow >> 1) & 3)) << 4);

  const char* gqh = (const char*)Qph + ((size_t)(bb * 7) * SS + m0) * 64;
  const char* gql = (const char*)Qpl + ((size_t)(bb * 7) * SS + m0) * 64;
  const char* gkh = (const char*)Kph + ((size_t)(bb * 7) * SS + n0) * 64;
  const char* gkl = (const char*)Kpl + ((size_t)(bb * 7) * SS + n0) * 64;

  const f32x4 fzero = {0.f, 0.f, 0.f, 0.f};
  f32x4 acc[2][4];
#pragma unroll
  for (int mf = 0; mf < 2; ++mf)
#pragma unroll
    for (int nf = 0; nf < 4; ++nf) acc[mf][nf] = fzero;

#define SSTAGE(buf, kk) do {                                            \
    size_t ko = (size_t)(kk) * (SS * 64);                               \
    gload16(gqh + ko + gc, &lds[buf][0][w << 4][0]);                    \
    gload16(gql + ko + gc, &lds[buf][1][w << 4][0]);                    \
    gload16(gkh + ko + gc, &lds[buf][2][w << 4][0]);                    \
    gload16(gkl + ko + gc, &lds[buf][3][w << 4][0]);                    \
  } while (0)

  SSTAGE(0, 0);
  __syncthreads();
#pragma unroll
  for (int t = 0; t < 7; ++t) {
    const int buf = t & 1;
    if (t < 6) SSTAGE(buf ^ 1, t + 1);
    bf16x8 ah[2], al[2];
#pragma unroll
    for (int mf = 0; mf < 2; ++mf) {
      int ar = wm * 32 + mf * 16 + lr;
      int ao = (lh ^ ((ar >> 1) & 3)) << 4;
      ah[mf] = *(const bf16x8*)&lds[buf][0][ar][ao];
      al[mf] = *(const bf16x8*)&lds[buf][1][ar][ao];
    }
#pragma unroll
    for (int nf = 0; nf < 4; ++nf) {
      int br = wn * 64 + nf * 16 + lr;
      int bo = (lh ^ ((br >> 1) & 3)) << 4;
      bf16x8 bh = *(const bf16x8*)&lds[buf][2][br][bo];
      bf16x8 bl = *(const bf16x8*)&lds[buf][3][br][bo];
#pragma unroll
      for (int mf = 0; mf < 2; ++mf) {
        acc[mf][nf] = __builtin_amdgcn_mfma_f32_16x16x32_bf16(ah[mf], bh, acc[mf][nf], 0, 0, 0);
        acc[mf][nf] = __builtin_amdgcn_mfma_f32_16x16x32_bf16(ah[mf], bl, acc[mf][nf], 0, 0, 0);
        acc[mf][nf] = __builtin_amdgcn_mfma_f32_16x16x32_bf16(al[mf], bh, acc[mf][nf], 0, 0, 0);
      }
    }
    __syncthreads();
  }
#undef SSTAGE

#pragma unroll
  for (int mf = 0; mf < 2; ++mf) {
#pragma unroll
    for (int r = 0; r < 4; ++r) {
      const int sr = m0 + wm * 32 + mf * 16 + lh * 4 + r;
      float z = 0.f;
#pragma unroll
      for (int nf = 0; nf < 4; ++nf) {
        const int tc = n0 + wn * 64 + nf * 16 + lr;
        float iv = isc[(size_t)sr * SS + tc];
        float sval = acc[mf][nf][r] * __builtin_amdgcn_rcpf(iv);
        float e = __expf(sval - MSHIFT);
        z += e;
        float mk = dmask[(size_t)bb * SS * SS + (size_t)sr * SS + tc];
        Pp[((size_t)(bb * 64 + (tc >> 5)) * SS + sr) * 32 + (tc & 31)] = f2bf(e * mk);
      }
#pragma unroll
      for (int off = 1; off < 16; off <<= 1) z += __shfl_xor(z, off);
      if (lr == 0) atomicAdd(&Z[bb * SS + sr], z);
    }
  }
}

// ---- pass 2: O = (P~ V) / Z. 2-phase LDS pipeline, k=2048 (32 steps of 64) ----
__global__ __launch_bounds__(512, 4)
void gemm_pv(const ushort* __restrict__ Pp, const ushort* __restrict__ Vp,
             const float* __restrict__ Z, float* __restrict__ out)
{
  const int bid = blockIdx.x;
  const int bb = bid & 7;
  const int tt = bid >> 3;
  const int m0 = (tt & 15) * 128;
  const int n0 = (tt >> 4) * 128;
  const int tid = threadIdx.x;
  const int w  = tid >> 6;
  const int l  = tid & 63;
  const int lr = l & 15;
  const int lh = l >> 4;
  const int wm = w & 3;
  const int wn = w >> 2;

  __shared__ __align__(16) char lds[2][2][2][128][64];   // 64 KB

  const int srow = (w << 4) + (l >> 2);
  const int ssl  = l & 3;
  const size_t gc = (size_t)srow * 64 + (size_t)((ssl ^ ((srow >> 1) & 3)) << 4);

  const char* gpb = (const char*)Pp + ((size_t)(bb * 64) * SS + m0) * 64;
  const char* gvb = (const char*)Vp + ((size_t)(bb * 64) * DD + n0) * 64;

  const f32x4 fzero = {0.f, 0.f, 0.f, 0.f};
  f32x4 acc[2][4];
#pragma unroll
  for (int mf = 0; mf < 2; ++mf)
#pragma unroll
    for (int nf = 0; nf < 4; ++nf) acc[mf][nf] = fzero;

#define PVSTAGE(buf, t) do {                                              \
    size_t k0 = (size_t)(t) * 2;                                          \
    gload16(gpb + k0 * (SS * 64) + gc,        &lds[buf][0][0][w << 4][0]); \
    gload16(gpb + (k0 + 1) * (SS * 64) + gc,  &lds[buf][0][1][w << 4][0]); \
    gload16(gvb + k0 * (DD * 64) + gc,        &lds[buf][1][0][w << 4][0]); \
    gload16(gvb + (k0 + 1) * (DD * 64) + gc,  &lds[buf][1][1][w << 4][0]); \
  } while (0)

  PVSTAGE(0, 0);
  __syncthreads();
  for (int t = 0; t < 32; ++t) {
    const int buf = t & 1;
    if (t < 31) PVSTAGE(buf ^ 1, t + 1);
#pragma unroll
    for (int pk = 0; pk < 2; ++pk) {
      bf16x8 af[2];
#pragma unroll
      for (int mf = 0; mf < 2; ++mf) {
        int ar = wm * 32 + mf * 16 + lr;
        int ao = (lh ^ ((ar >> 1) & 3)) << 4;
        af[mf] = *(const bf16x8*)&lds[buf][0][pk][ar][ao];
      }
#pragma unroll
      for (int nf = 0; nf < 4; ++nf) {
        int br = wn * 64 + nf * 16 + lr;
        int bo = (lh ^ ((br >> 1) & 3)) << 4;
        bf16x8 bfr = *(const bf16x8*)&lds[buf][1][pk][br][bo];
#pragma unroll
        for (int mf = 0; mf < 2; ++mf)
          acc[mf][nf] = __builtin_amdgcn_mfma_f32_16x16x32_bf16(af[mf], bfr, acc[mf][nf], 0, 0, 0);
      }
    }
    __syncthreads();
  }
#undef PVSTAGE

#pragma unroll
  for (int mf = 0; mf < 2; ++mf) {
#pragma unroll
    for (int r = 0; r < 4; ++r) {
      const int sr = m0 + wm * 32 + mf * 16 + lh * 4 + r;
      float rz = __builtin_amdgcn_rcpf(Z[bb * SS + sr]);
#pragma unroll
      for (int nf = 0; nf < 4; ++nf) {
        const int dc = n0 + wn * 64 + nf * 16 + lr;
        out[((size_t)bb * SS + sr) * DD + dc] = acc[mf][nf][r] * rz;
      }
    }
  }
}

extern "C" void kernel_launch(void* const* d_in, const int* in_sizes, int n_in,
                              void* d_out, int out_size, void* d_ws, size_t ws_size,
                              hipStream_t stream) {
  const float* x1  = (const float*)d_in[0];
  const float* x2  = (const float*)d_in[1];
  const float* x3  = (const float*)d_in[2];
  const float* Wq  = (const float*)d_in[3];
  const float* bq  = (const float*)d_in[4];
  const float* Wk  = (const float*)d_in[5];
  const float* bk  = (const float*)d_in[6];
  const float* Wv  = (const float*)d_in[7];
  const float* bv  = (const float*)d_in[8];
  const float* isc = (const float*)d_in[9];
  const float* dmk = (const float*)d_in[10];
  float* out = (float*)d_out;

  const size_t QKN = (size_t)NB * 7 * SS * 32;
  const size_t VPN = (size_t)NB * 64 * DD * 32;
  const size_t WN  = (size_t)WROWS * DD;
  const size_t NV  = (size_t)DD * DD;
  const size_t PPN = (size_t)NB * 64 * SS * 32;

  ushort* Qph = (ushort*)d_ws;
  ushort* Qpl = Qph + QKN;
  ushort* Kph = Qpl + QKN;
  ushort* Kpl = Kph + QKN;
  ushort* Vp  = Kpl + QKN;
  ushort* Wqh = Vp + VPN;
  ushort* Wql = Wqh + WN;
  ushort* Wkh = Wql + WN;
  ushort* Wkl = Wkh + WN;
  ushort* Wvb = Wkl + WN;
  ushort* Pp  = Wvb + NV;
  float*  Zb  = (float*)(Pp + PPN);

  dim3 blk(256);
  prep_w<<<dim3(512), blk, 0, stream>>>(Wq, Wk, Wv, Wqh, Wql, Wkh, Wkl, Wvb, Zb);
  gemm_qk<<<dim3(256, 4), blk, 0, stream>>>(x1, x2, Wqh, Wql, Wkh, Wkl, bq, bk,
                                            Qph, Qpl, Kph, Kpl);
  gemm_v <<<dim3(256, 3), blk, 0, stream>>>(x3, Wvb, bv, Vp);
  gemm_s <<<dim3(2048), dim3(512), 0, stream>>>(Qph, Qpl, Kph, Kpl, isc, dmk, Pp, Zb);
  gemm_pv<<<dim3(768),  dim3(512), 0, stream>>>(Pp, Vp, Zb, out);
}

// Round 12
// 273.575 us; speedup vs baseline: 2.5910x; 1.0361x over previous
//
#include <hip/hip_runtime.h>
#include <hip/hip_bf16.h>

typedef unsigned short ushort;
typedef short bf16x8 __attribute__((ext_vector_type(8)));
typedef float f32x4 __attribute__((ext_vector_type(4)));

#define NB 8
#define SS 2048
#define DD 768
#define DKV 214
#define DKP 224
#define WROWS 256
#define MSHIFT 40.0f

__device__ __forceinline__ float bf2f(ushort u) {
  union { unsigned int i; float f; } v; v.i = ((unsigned int)u) << 16; return v.f;
}
__device__ __forceinline__ ushort f2bf(float f) {
  union { float f; unsigned int i; } v; v.f = f;
  unsigned int x = v.i;
  return (ushort)((x + 0x7fffu + ((x >> 16) & 1u)) >> 16);
}
__device__ __forceinline__ void split8v(f32x4 a, f32x4 b, bf16x8& h, bf16x8& l) {
#pragma unroll
  for (int j = 0; j < 4; ++j) {
    ushort h0 = f2bf(a[j]); h[j]     = (short)h0; l[j]     = (short)f2bf(a[j] - bf2f(h0));
    ushort h1 = f2bf(b[j]); h[j + 4] = (short)h1; l[j + 4] = (short)f2bf(b[j] - bf2f(h1));
  }
}
__device__ __forceinline__ bf16x8 cvt8v(f32x4 a, f32x4 b) {
  bf16x8 r;
#pragma unroll
  for (int j = 0; j < 4; ++j) { r[j] = (short)f2bf(a[j]); r[j + 4] = (short)f2bf(b[j]); }
  return r;
}
// async global->LDS, 16B per lane; LDS dest is wave-uniform base + lane*16
__device__ __forceinline__ void gload16(const void* g, void* l) {
  __builtin_amdgcn_global_load_lds(
      (const __attribute__((address_space(1))) void*)g,
      (__attribute__((address_space(3))) void*)l, 16, 0, 0);
}

// ---- weight prep + Z zero. Wq,Wk -> k-packed [24][256][32] hi/lo; Wv -> [24][768][32] ----
__global__ __launch_bounds__(256)
void prep_w(const float* __restrict__ Wq, const float* __restrict__ Wk,
            const float* __restrict__ Wv,
            ushort* __restrict__ Wqh, ushort* __restrict__ Wql,
            ushort* __restrict__ Wkh, ushort* __restrict__ Wkl,
            ushort* __restrict__ Wvb, float* __restrict__ Z)
{
  const int NW = WROWS * DD;
  const int NV = DD * DD;
  for (int i = blockIdx.x * 256 + threadIdx.x; i < NB * SS; i += gridDim.x * 256)
    Z[i] = 0.f;
  for (int i = blockIdx.x * 256 + threadIdx.x; i < 2 * NW + NV; i += gridDim.x * 256) {
    if (i < NW) {
      int r = i / DD, c = i % DD;
      float v = (r < DKV) ? Wq[i] : 0.f;
      ushort h = f2bf(v);
      int d = (c >> 5) * (WROWS * 32) + r * 32 + (c & 31);
      Wqh[d] = h; Wql[d] = f2bf(v - bf2f(h));
    } else if (i < 2 * NW) {
      int j = i - NW;
      int r = j / DD, c = j % DD;
      float v = (r < DKV) ? Wk[j] : 0.f;
      ushort h = f2bf(v);
      int d = (c >> 5) * (WROWS * 32) + r * 32 + (c & 31);
      Wkh[d] = h; Wkl[d] = f2bf(v - bf2f(h));
    } else {
      int j = i - 2 * NW;
      int r = j / DD, c = j % DD;
      Wvb[(c >> 5) * (DD * 32) + r * 32 + (c & 31)] = f2bf(Wv[j]);
    }
  }
}

// ---- fused Q+K projection -> k-packed hi/lo [b][7][2048][32] (unchanged R11) ----
__global__ __launch_bounds__(256, 4)
void gemm_qk(const float* __restrict__ x1, const float* __restrict__ x2,
             const ushort* __restrict__ Wqh, const ushort* __restrict__ Wql,
             const ushort* __restrict__ Wkh, const ushort* __restrict__ Wkl,
             const float* __restrict__ bq, const float* __restrict__ bk,
             ushort* __restrict__ Qph, ushort* __restrict__ Qpl,
             ushort* __restrict__ Kph, ushort* __restrict__ Kpl)
{
  const int m0 = blockIdx.x * 64;
  const int which = blockIdx.y >> 1;
  const int n0 = (blockIdx.y & 1) * 128;
  const int tid = threadIdx.x;
  const int w  = tid >> 6;
  const int l  = tid & 63;
  const int lr = l & 15;
  const int lh = l >> 4;

  const float*  A    = which ? x2 : x1;
  const ushort* Bh   = which ? Wkh : Wqh;
  const ushort* Bl   = which ? Wkl : Wql;
  const float*  bias = which ? bk : bq;
  ushort* Ch = which ? Kph : Qph;
  ushort* Cl = which ? Kpl : Qpl;

  __shared__ __align__(16) char lds[2][2][128][64];

  const int srow = (w << 4) + (l >> 2);
  const size_t gc = (size_t)srow * 64 + (size_t)((((l & 3) ^ ((srow >> 1) & 3))) << 4);
  const char* gbh = (const char*)Bh + (size_t)n0 * 64;
  const char* gbl = (const char*)Bl + (size_t)n0 * 64;

  const f32x4 fzero = {0.f, 0.f, 0.f, 0.f};
  f32x4 acc[8];
#pragma unroll
  for (int nt = 0; nt < 8; ++nt) acc[nt] = fzero;

  const float* arow = A + (size_t)(m0 + w * 16 + lr) * DD + lh * 8;

#define QKSTAGE(buf, kk) do {                                             \
    size_t ko = (size_t)(kk) * (WROWS * 64);                              \
    gload16(gbh + ko + gc,        &lds[buf][0][w << 4][0]);               \
    gload16(gbh + ko + gc + 4096, &lds[buf][0][(w << 4) + 64][0]);        \
    gload16(gbl + ko + gc,        &lds[buf][1][w << 4][0]);               \
    gload16(gbl + ko + gc + 4096, &lds[buf][1][(w << 4) + 64][0]);        \
  } while (0)

  QKSTAGE(0, 0);
  f32x4 pa = *(const f32x4*)(arow);
  f32x4 pb = *(const f32x4*)(arow + 4);
  __syncthreads();

  for (int kk = 0; kk < 24; ++kk) {
    const int buf = kk & 1;
    if (kk < 23) QKSTAGE(buf ^ 1, kk + 1);
    f32x4 na = fzero, nb = fzero;
    if (kk < 23) {
      na = *(const f32x4*)(arow + (kk + 1) * 32);
      nb = *(const f32x4*)(arow + (kk + 1) * 32 + 4);
    }
    bf16x8 ah, al; split8v(pa, pb, ah, al);
#pragma unroll
    for (int nt = 0; nt < 8; ++nt) {
      int br = nt * 16 + lr;
      int bo = (lh ^ ((br >> 1) & 3)) << 4;
      bf16x8 wh = *(const bf16x8*)&lds[buf][0][br][bo];
      bf16x8 wl = *(const bf16x8*)&lds[buf][1][br][bo];
      acc[nt] = __builtin_amdgcn_mfma_f32_16x16x32_bf16(ah, wh, acc[nt], 0, 0, 0);
      acc[nt] = __builtin_amdgcn_mfma_f32_16x16x32_bf16(ah, wl, acc[nt], 0, 0, 0);
      acc[nt] = __builtin_amdgcn_mfma_f32_16x16x32_bf16(al, wh, acc[nt], 0, 0, 0);
    }
    __syncthreads();
    pa = na; pb = nb;
  }
#undef QKSTAGE

#pragma unroll
  for (int nt = 0; nt < 8; ++nt) {
    int n = n0 + nt * 16 + lr;
    if (n >= DKP) continue;
    float bv = (n < DKV) ? bias[n] : 0.f;
#pragma unroll
    for (int r = 0; r < 4; ++r) {
      int m = m0 + w * 16 + lh * 4 + r;
      int bb = m >> 11, s = m & 2047;
      float val = (n < DKV) ? (acc[nt][r] + bv) : 0.f;
      ushort h = f2bf(val);
      size_t idx = ((size_t)(bb * 7 + (n >> 5)) * SS + s) * 32 + (n & 31);
      Ch[idx] = h;
      Cl[idx] = f2bf(val - bf2f(h));
    }
  }
}

// ---- V projection -> k-packed Vp[b][64][768][32] (unchanged R11) ----
__global__ __launch_bounds__(256, 3)
void gemm_v(const float* __restrict__ A, const ushort* __restrict__ Bw,
            const float* __restrict__ bias, ushort* __restrict__ Vp)
{
  const int m0 = blockIdx.x * 64;
  const int n0 = blockIdx.y * 256;
  const int tid = threadIdx.x;
  const int w  = tid >> 6;
  const int l  = tid & 63;
  const int lr = l & 15;
  const int lh = l >> 4;

  __shared__ __align__(16) char smem[36864];
  typedef char VBuf[256][64];
  VBuf* stage = (VBuf*)smem;
  ushort (*lt)[72] = (ushort(*)[72])smem;

  const int srow = (w << 4) + (l >> 2);
  const size_t gc = (size_t)srow * 64 + (size_t)((((l & 3) ^ ((srow >> 1) & 3))) << 4);
  const char* gvw = (const char*)Bw + (size_t)n0 * 64;

  const f32x4 fzero = {0.f, 0.f, 0.f, 0.f};
  f32x4 acc[16];
#pragma unroll
  for (int nt = 0; nt < 16; ++nt) acc[nt] = fzero;

  const float* arow = A + (size_t)(m0 + w * 16 + lr) * DD + lh * 8;

#define VSTAGE(buf, kk) do {                                              \
    size_t ko = (size_t)(kk) * (DD * 64);                                 \
    gload16(gvw + ko + gc,         &stage[buf][w << 4][0]);               \
    gload16(gvw + ko + gc + 4096,  &stage[buf][(w << 4) + 64][0]);        \
    gload16(gvw + ko + gc + 8192,  &stage[buf][(w << 4) + 128][0]);       \
    gload16(gvw + ko + gc + 12288, &stage[buf][(w << 4) + 192][0]);       \
  } while (0)

  VSTAGE(0, 0);
  f32x4 pa = *(const f32x4*)(arow);
  f32x4 pb = *(const f32x4*)(arow + 4);
  __syncthreads();

  for (int kk = 0; kk < 24; ++kk) {
    const int buf = kk & 1;
    if (kk < 23) VSTAGE(buf ^ 1, kk + 1);
    f32x4 na = fzero, nb = fzero;
    if (kk < 23) {
      na = *(const f32x4*)(arow + (kk + 1) * 32);
      nb = *(const f32x4*)(arow + (kk + 1) * 32 + 4);
    }
    bf16x8 af = cvt8v(pa, pb);
#pragma unroll
    for (int nt = 0; nt < 16; ++nt) {
      int br = nt * 16 + lr;
      int bo = (lh ^ ((br >> 1) & 3)) << 4;
      bf16x8 bfr = *(const bf16x8*)&stage[buf][br][bo];
      acc[nt] = __builtin_amdgcn_mfma_f32_16x16x32_bf16(af, bfr, acc[nt], 0, 0, 0);
    }
    __syncthreads();
    pa = na; pb = nb;
  }
#undef VSTAGE

#pragma unroll
  for (int nt = 0; nt < 16; ++nt) {
    int nl = nt * 16 + lr;
    float bv = bias[n0 + nl];
#pragma unroll
    for (int r = 0; r < 4; ++r)
      lt[nl][w * 16 + lh * 4 + r] = f2bf(acc[nt][r] + bv);
  }
  __syncthreads();
  const int bb = m0 >> 11;
  const int s0 = m0 & 2047;
  for (int i = tid; i < 256 * 64; i += 256) {
    int nn = i >> 6, mm = i & 63;
    int d = n0 + nn, t = s0 + mm;
    Vp[((size_t)(bb * 64 + (t >> 5)) * DD + d) * 32 + (t & 31)] = lt[nn][mm];
  }
}

// ---- pass 1: S = QK^T (split-bf16). Tile 128m x 256n, 8 waves of 64x64,
// acc[4][4], single-buffered 48 KB LDS (2 barriers/step), ratio 3.0 MFMA/ds_read.
__global__ __launch_bounds__(512, 4)
void gemm_s(const ushort* __restrict__ Qph, const ushort* __restrict__ Qpl,
            const ushort* __restrict__ Kph, const ushort* __restrict__ Kpl,
            const float* __restrict__ isc, const float* __restrict__ dmask,
            ushort* __restrict__ Pp, float* __restrict__ Z)
{
  const int bid = blockIdx.x;
  const int bb = bid & 7;
  const int tt = bid >> 3;                // 0..127
  const int m0 = (tt & 15) * 128;
  const int n0 = (tt >> 4) * 256;
  const int tid = threadIdx.x;
  const int w  = tid >> 6;
  const int l  = tid & 63;
  const int lr = l & 15;
  const int lh = l >> 4;
  const int wm = w & 1;                   // 2 m-groups of 64
  const int wn = w >> 1;                  // 4 n-groups of 64

  __shared__ __align__(16) char Qhb[128][64];   // 8 KB
  __shared__ __align__(16) char Qlb[128][64];
  __shared__ __align__(16) char Khb[256][64];   // 16 KB
  __shared__ __align__(16) char Klb[256][64];   // total 48 KB

  const int srow = (w << 4) + (l >> 2);
  const size_t gc = (size_t)srow * 64 + (size_t)((((l & 3) ^ ((srow >> 1) & 3))) << 4);

  const char* gqh = (const char*)Qph + ((size_t)(bb * 7) * SS + m0) * 64;
  const char* gql = (const char*)Qpl + ((size_t)(bb * 7) * SS + m0) * 64;
  const char* gkh = (const char*)Kph + ((size_t)(bb * 7) * SS + n0) * 64;
  const char* gkl = (const char*)Kpl + ((size_t)(bb * 7) * SS + n0) * 64;

  const f32x4 fzero = {0.f, 0.f, 0.f, 0.f};
  f32x4 acc[4][4];
#pragma unroll
  for (int mf = 0; mf < 4; ++mf)
#pragma unroll
    for (int nf = 0; nf < 4; ++nf) acc[mf][nf] = fzero;

#define SSTAGE(kk) do {                                                 \
    size_t ko = (size_t)(kk) * (SS * 64);                               \
    gload16(gqh + ko + gc,        &Qhb[w << 4][0]);                     \
    gload16(gql + ko + gc,        &Qlb[w << 4][0]);                     \
    gload16(gkh + ko + gc,        &Khb[w << 4][0]);                     \
    gload16(gkh + ko + gc + 8192, &Khb[(w << 4) + 128][0]);             \
    gload16(gkl + ko + gc,        &Klb[w << 4][0]);                     \
    gload16(gkl + ko + gc + 8192, &Klb[(w << 4) + 128][0]);             \
  } while (0)

  SSTAGE(0);
  __syncthreads();
#pragma unroll 1
  for (int t = 0; t < 7; ++t) {
    // B fragments once (32 VGPR), reused by all 4 mf groups
    bf16x8 bh[4], bl[4];
#pragma unroll
    for (int nf = 0; nf < 4; ++nf) {
      int br = wn * 64 + nf * 16 + lr;
      int bo = (lh ^ ((br >> 1) & 3)) << 4;
      bh[nf] = *(const bf16x8*)&Khb[br][bo];
      bl[nf] = *(const bf16x8*)&Klb[br][bo];
    }
#pragma unroll
    for (int mf = 0; mf < 4; ++mf) {
      int ar = wm * 64 + mf * 16 + lr;
      int ao = (lh ^ ((ar >> 1) & 3)) << 4;
      bf16x8 ah = *(const bf16x8*)&Qhb[ar][ao];
      bf16x8 al = *(const bf16x8*)&Qlb[ar][ao];
#pragma unroll
      for (int nf = 0; nf < 4; ++nf) {
        acc[mf][nf] = __builtin_amdgcn_mfma_f32_16x16x32_bf16(ah, bh[nf], acc[mf][nf], 0, 0, 0);
        acc[mf][nf] = __builtin_amdgcn_mfma_f32_16x16x32_bf16(ah, bl[nf], acc[mf][nf], 0, 0, 0);
        acc[mf][nf] = __builtin_amdgcn_mfma_f32_16x16x32_bf16(al, bh[nf], acc[mf][nf], 0, 0, 0);
      }
    }
    __syncthreads();                 // readers done
    if (t < 6) {
      SSTAGE(t + 1);                 // overwrite single buffer
      __syncthreads();               // staging landed (vmcnt drained)
    }
  }
#undef SSTAGE

  // epilogue: scale, exp(.-MSHIFT), Z partial sums (atomic), P~ store
#pragma unroll
  for (int mf = 0; mf < 4; ++mf) {
#pragma unroll
    for (int r = 0; r < 4; ++r) {
      const int sr = m0 + wm * 64 + mf * 16 + lh * 4 + r;
      float z = 0.f;
#pragma unroll
      for (int nf = 0; nf < 4; ++nf) {
        const int tc = n0 + wn * 64 + nf * 16 + lr;
        float iv = isc[(size_t)sr * SS + tc];
        float sval = acc[mf][nf][r] * __builtin_amdgcn_rcpf(iv);
        float e = __expf(sval - MSHIFT);
        z += e;
        float mk = dmask[(size_t)bb * SS * SS + (size_t)sr * SS + tc];
        Pp[((size_t)(bb * 64 + (tc >> 5)) * SS + sr) * 32 + (tc & 31)] = f2bf(e * mk);
      }
#pragma unroll
      for (int off = 1; off < 16; off <<= 1) z += __shfl_xor(z, off);
      if (lr == 0) atomicAdd(&Z[bb * SS + sr], z);
    }
  }
}

// ---- pass 2: O = (P~ V) / Z. Tile 128x128, 4 waves of 64x64, acc[4][4],
// single-buffered 32 KB LDS, ratio 2.0 MFMA/ds_read. k = 2048 (32 steps of 64).
__global__ __launch_bounds__(256, 4)
void gemm_pv(const ushort* __restrict__ Pp, const ushort* __restrict__ Vp,
             const float* __restrict__ Z, float* __restrict__ out)
{
  const int bid = blockIdx.x;
  const int bb = bid & 7;
  const int tt = bid >> 3;
  const int m0 = (tt & 15) * 128;
  const int n0 = (tt >> 4) * 128;
  const int tid = threadIdx.x;
  const int w  = tid >> 6;
  const int l  = tid & 63;
  const int lr = l & 15;
  const int lh = l >> 4;
  const int wm = w & 1;
  const int wn = w >> 1;

  __shared__ __align__(16) char Plb[2][128][64];   // [pack][row][byte] 16 KB
  __shared__ __align__(16) char Vlb[2][128][64];   // 16 KB

  const int srow = (w << 4) + (l >> 2);
  const size_t gc = (size_t)srow * 64 + (size_t)((((l & 3) ^ ((srow >> 1) & 3))) << 4);

  const char* gpb = (const char*)Pp + ((size_t)(bb * 64) * SS + m0) * 64;
  const char* gvb = (const char*)Vp + ((size_t)(bb * 64) * DD + n0) * 64;

  const f32x4 fzero = {0.f, 0.f, 0.f, 0.f};
  f32x4 acc[4][4];
#pragma unroll
  for (int mf = 0; mf < 4; ++mf)
#pragma unroll
    for (int nf = 0; nf < 4; ++nf) acc[mf][nf] = fzero;

#define PVSTAGE(t) do {                                                   \
    size_t k0 = (size_t)(t) * 2;                                          \
    gload16(gpb + k0 * (SS * 64) + gc,              &Plb[0][w << 4][0]);  \
    gload16(gpb + k0 * (SS * 64) + gc + 4096,       &Plb[0][(w << 4) + 64][0]); \
    gload16(gpb + (k0 + 1) * (SS * 64) + gc,        &Plb[1][w << 4][0]);  \
    gload16(gpb + (k0 + 1) * (SS * 64) + gc + 4096, &Plb[1][(w << 4) + 64][0]); \
    gload16(gvb + k0 * (DD * 64) + gc,              &Vlb[0][w << 4][0]);  \
    gload16(gvb + k0 * (DD * 64) + gc + 4096,       &Vlb[0][(w << 4) + 64][0]); \
    gload16(gvb + (k0 + 1) * (DD * 64) + gc,        &Vlb[1][w << 4][0]);  \
    gload16(gvb + (k0 + 1) * (DD * 64) + gc + 4096, &Vlb[1][(w << 4) + 64][0]); \
  } while (0)

  PVSTAGE(0);
  __syncthreads();
#pragma unroll 1
  for (int t = 0; t < 32; ++t) {
#pragma unroll
    for (int pk = 0; pk < 2; ++pk) {
      bf16x8 bfr[4];
#pragma unroll
      for (int nf = 0; nf < 4; ++nf) {
        int br = wn * 64 + nf * 16 + lr;
        int bo = (lh ^ ((br >> 1) & 3)) << 4;
        bfr[nf] = *(const bf16x8*)&Vlb[pk][br][bo];
      }
#pragma unroll
      for (int mf = 0; mf < 4; ++mf) {
        int ar = wm * 64 + mf * 16 + lr;
        int ao = (lh ^ ((ar >> 1) & 3)) << 4;
        bf16x8 af = *(const bf16x8*)&Plb[pk][ar][ao];
#pragma unroll
        for (int nf = 0; nf < 4; ++nf)
          acc[mf][nf] = __builtin_amdgcn_mfma_f32_16x16x32_bf16(af, bfr[nf], acc[mf][nf], 0, 0, 0);
      }
    }
    __syncthreads();
    if (t < 31) {
      PVSTAGE(t + 1);
      __syncthreads();
    }
  }
#undef PVSTAGE

#pragma unroll
  for (int mf = 0; mf < 4; ++mf) {
#pragma unroll
    for (int r = 0; r < 4; ++r) {
      const int sr = m0 + wm * 64 + mf * 16 + lh * 4 + r;
      float rz = __builtin_amdgcn_rcpf(Z[bb * SS + sr]);
#pragma unroll
      for (int nf = 0; nf < 4; ++nf) {
        const int dc = n0 + wn * 64 + nf * 16 + lr;
        out[((size_t)bb * SS + sr) * DD + dc] = acc[mf][nf][r] * rz;
      }
    }
  }
}

extern "C" void kernel_launch(void* const* d_in, const int* in_sizes, int n_in,
                              void* d_out, int out_size, void* d_ws, size_t ws_size,
                              hipStream_t stream) {
  const float* x1  = (const float*)d_in[0];
  const float* x2  = (const float*)d_in[1];
  const float* x3  = (const float*)d_in[2];
  const float* Wq  = (const float*)d_in[3];
  const float* bq  = (const float*)d_in[4];
  const float* Wk  = (const float*)d_in[5];
  const float* bk  = (const float*)d_in[6];
  const float* Wv  = (const float*)d_in[7];
  const float* bv  = (const float*)d_in[8];
  const float* isc = (const float*)d_in[9];
  const float* dmk = (const float*)d_in[10];
  float* out = (float*)d_out;

  const size_t QKN = (size_t)NB * 7 * SS * 32;
  const size_t VPN = (size_t)NB * 64 * DD * 32;
  const size_t WN  = (size_t)WROWS * DD;
  const size_t NV  = (size_t)DD * DD;
  const size_t PPN = (size_t)NB * 64 * SS * 32;

  ushort* Qph = (ushort*)d_ws;
  ushort* Qpl = Qph + QKN;
  ushort* Kph = Qpl + QKN;
  ushort* Kpl = Kph + QKN;
  ushort* Vp  = Kpl + QKN;
  ushort* Wqh = Vp + VPN;
  ushort* Wql = Wqh + WN;
  ushort* Wkh = Wql + WN;
  ushort* Wkl = Wkh + WN;
  ushort* Wvb = Wkl + WN;
  ushort* Pp  = Wvb + NV;
  float*  Zb  = (float*)(Pp + PPN);

  dim3 blk(256);
  prep_w<<<dim3(512), blk, 0, stream>>>(Wq, Wk, Wv, Wqh, Wql, Wkh, Wkl, Wvb, Zb);
  gemm_qk<<<dim3(256, 4), blk, 0, stream>>>(x1, x2, Wqh, Wql, Wkh, Wkl, bq, bk,
                                            Qph, Qpl, Kph, Kpl);
  gemm_v <<<dim3(256, 3), blk, 0, stream>>>(x3, Wvb, bv, Vp);
  gemm_s <<<dim3(1024), dim3(512), 0, stream>>>(Qph, Qpl, Kph, Kpl, isc, dmk, Pp, Zb);
  gemm_pv<<<dim3(768),  dim3(256), 0, stream>>>(Pp, Vp, Zb, out);
}